// Round 5
// baseline (7107.104 us; speedup 1.0000x reference)
//
#include <hip/hip_runtime.h>

#define B_    64
#define T_    1024
#define IN_   64
#define H_    512
#define OUT_  64
#define SLOTS 8
#define NWG   130
#define NWORD 6144      // words per (bhalf, slot): 32 jt * 32 rows * 6 words

typedef _Float16 f16;
typedef _Float16 half8 __attribute__((ext_vector_type(8)));
typedef float    floatx4 __attribute__((ext_vector_type(4)));
typedef unsigned int u32;
typedef unsigned short u16;
typedef unsigned long long u64;

#define MFMA16(a,b,c) __builtin_amdgcn_mfma_f32_16x16x32_f16((a),(b),(c),0,0,0)

// LDS layout (158720 B, 1 WG/CU)
// H1W/H2W hold RAW tagged words [jt][row][7] (row stride 7 u64 = 56B -> 16-bank spread)
#define XS_OFF   0        // 8KB: L1 x-stage (dense fp32, swizzled as R5)
#define RED_OFF  11264    // 32KB: 4 kq-regions x 8KB partial-sum
#define H1W_OFF  44032    // 57344: packed h words (h1 for L1/L2; h2 for head)
#define H2W_OFF  101376   // 57344: packed h2 words (L2 pass B)

__device__ __forceinline__ float sigmoidf_(float x) {
    return 1.0f / (1.0f + __expf(-x));
}
__device__ __forceinline__ float tanhf_(float x) {
    float ax = fabsf(x);
    float e  = __expf(-2.0f * ax);
    float t  = (1.0f - e) / (1.0f + e);
    return x >= 0.0f ? t : -t;
}

// Flags: agent-scope RMW + agent-scope poll (proven R2/R5). Back-pressure edges only.
__device__ __forceinline__ void wait_ge(u32* p, u32 v) {
    while (__hip_atomic_load(p, __ATOMIC_RELAXED, __HIP_MEMORY_SCOPE_AGENT) < v)
        __builtin_amdgcn_s_sleep(1);
}
__device__ __forceinline__ void flag_add(u32* p) {
    __hip_atomic_fetch_add(p, 1u, __ATOMIC_RELAXED, __HIP_MEMORY_SCOPE_AGENT);
}
// Back-pressure flags are time-ordered per producer group (each WG finishes steps
// in order), so a probe 4 ahead that passes covers the next 4 iterations too.
__device__ __forceinline__ void cached_wait(u32* arr, int need, u32 thr, int* cache) {
    if (need <= *cache) return;
    int probe = need + 4; if (probe > T_ - 1) probe = T_ - 1;
    if (__hip_atomic_load(arr + probe, __ATOMIC_RELAXED, __HIP_MEMORY_SCOPE_AGENT) >= thr) {
        *cache = probe; return;
    }
    wait_ge(arr + need, thr);
    *cache = need;
}
// Tagged-word publish: relaxed system-scope atomic store. Tag is IN the word ->
// no ordering vs anything else is needed; word is self-validating.
__device__ __forceinline__ void astore8w(u64* p, u64 v) {
    __hip_atomic_store(p, v, __ATOMIC_RELAXED, __HIP_MEMORY_SCOPE_SYSTEM);
}
__device__ __forceinline__ u64 aload8w(const u64* p) {
    return __hip_atomic_load(p, __ATOMIC_RELAXED, __HIP_MEMORY_SCOPE_SYSTEM);
}

// Poll-stage ONE 49KB tagged buffer (6144 words) into LDS.
__device__ __forceinline__ void stage_poll(char* smem, int ldsOff, const u64* g,
                                           u32 exp, int tid, const int* soff) {
    u32 pend = 0xFFFu;
    do {
        u64 vv[12];
        #pragma unroll
        for (int i = 0; i < 12; ++i)
            vv[i] = aload8w(g + i*512 + tid);
        #pragma unroll
        for (int i = 0; i < 12; ++i) {
            if ((pend & (1u << i)) && (u32)(vv[i] >> 48) == exp) {
                *(u64*)(smem + ldsOff + soff[i]) = vv[i];
                pend &= ~(1u << i);
            }
        }
        if (pend) __builtin_amdgcn_s_sleep(1);
    } while (pend);
}

// Poll-stage TWO tagged buffers with INTERLEAVED loads (24 in flight): one MALL
// round trip covers both when satisfied, vs two serial RTs in R9. (R10 core fix)
__device__ __forceinline__ void stage_poll2(char* smem, const u64* g1, u32 e1,
                                            const u64* g2, u32 e2,
                                            int tid, const int* soff) {
    u32 p1 = 0xFFFu, p2 = 0xFFFu;
    do {
        u64 v1[12], v2[12];
        #pragma unroll
        for (int i = 0; i < 12; ++i) {
            v2[i] = aload8w(g2 + i*512 + tid);   // h2 first: the likely-pending one
            v1[i] = aload8w(g1 + i*512 + tid);
        }
        #pragma unroll
        for (int i = 0; i < 12; ++i) {
            if ((p2 & (1u << i)) && (u32)(v2[i] >> 48) == e2) {
                *(u64*)(smem + H2W_OFF + soff[i]) = v2[i];
                p2 &= ~(1u << i);
            }
            if ((p1 & (1u << i)) && (u32)(v1[i] >> 48) == e1) {
                *(u64*)(smem + H1W_OFF + soff[i]) = v1[i];
                p1 &= ~(1u << i);
            }
        }
        if (p1 | p2) __builtin_amdgcn_s_sleep(1);
    } while (p1 | p2);
}

// Build a half8 fragment (8 consecutive k-values) from 3 packed LDS words.
__device__ __forceinline__ half8 frag_pk(const char* p) {
    const u64* q = (const u64*)p;
    u64 w0 = q[0], w1 = q[1], w2 = q[2];
    u32 b = (u32)(w0 >> 32), c = (u32)w1, d = (u32)(w1 >> 32);
    union { u32 u[4]; half8 h; } U;
    U.u[0] = (u32)w0;
    U.u[1] = (b & 0xffffu) | (c << 16);
    U.u[2] = (c >> 16) | (d << 16);
    U.u[3] = (u32)w2;
    return U.h;
}
// LDS byte offset of word (jt, row, wi): ((jt*32+row)*7 + wi)*8
#define WB(jt,row,wi) (((jt)*224 + (row)*7 + (wi)) * 8)

// Publish this thread's h value (row=tid>>4, col=tid&15) directly from registers:
// each wave holds 4 complete rows (16 cols = 16 adjacent lanes), so 24 publisher
// lanes gather 3 cols each via in-wave shuffles. No LDS bounce, no barrier.
__device__ __forceinline__ void shuf_publish(u64* dst, int tid, int tag, float hf) {
    union { f16 h; u16 u; } cv; cv.h = (f16)hf;
    int hv = cv.u;
    const int l  = tid & 63;
    const int wv = tid >> 6;
    const int rj = l / 6;        // row-in-wave for publisher lanes (<24)
    const int pi = l - rj*6;     // word index 0..5
    const int pj = pi % 3;
    const int pcb = (pi/3)*8 + pj*3;
    const int s0 = (rj*16 + pcb)     & 63;
    const int s1 = (rj*16 + pcb + 1) & 63;
    const int s2 = (rj*16 + pcb + 2) & 63;
    int v0 = __shfl(hv, s0, 64);
    int v1 = __shfl(hv, s1, 64);
    int v2 = __shfl(hv, s2, 64);
    if (l < 24) {
        u64 wvd = (u64)(u16)v0 | ((u64)(u16)v1 << 16)
                | ((pj < 2) ? ((u64)(u16)v2 << 32) : 0)
                | ((u64)(u32)tag << 48);
        const int row = wv*4 + rj;
        astore8w(dst + row*6 + pi, wvd);
    }
}

// ---------------- prep kernels (weights -> fp16 fragment-linear) ----------------
__global__ void pack_w1(const float* __restrict__ Wih, const float* __restrict__ Whh,
                        f16* __restrict__ Wp) {
    int idx = blockIdx.x * 256 + threadIdx.x;
    if (idx >= 4*32*18*512) return;
    int j    = idx & 7;
    int lane = (idx >> 3) & 63;
    int kt   = (idx >> 9) % 18;
    int r    = (idx >> 9) / 18;
    int jt   = r & 31;
    int g    = r >> 5;
    int n = g*512 + jt*16 + (lane & 15);
    int k = kt*32 + (lane >> 4)*8 + j;
    float v = (k < 64) ? Wih[n*64 + k] : Whh[n*512 + (k - 64)];
    Wp[idx] = (f16)v;
}

__global__ void pack_w2(const float* __restrict__ Wih, const float* __restrict__ Whh,
                        f16* __restrict__ Wp) {
    int idx = blockIdx.x * 256 + threadIdx.x;
    if (idx >= 4*32*32*512) return;
    int j    = idx & 7;
    int lane = (idx >> 3) & 63;
    int kt   = (idx >> 9) & 31;
    int r    = idx >> 14;
    int jt   = r & 31;
    int g    = r >> 5;
    int n = g*512 + jt*16 + (lane & 15);
    int k = kt*32 + (lane >> 4)*8 + j;
    float v = (k < 512) ? Wih[n*512 + k] : Whh[n*512 + (k - 512)];
    Wp[idx] = (f16)v;
}

__global__ void pack_wo(const float* __restrict__ Wout, f16* __restrict__ Wp) {
    int idx = blockIdx.x * 256 + threadIdx.x;
    if (idx >= 4*16*512) return;
    int j    = idx & 7;
    int lane = (idx >> 3) & 63;
    int kt   = (idx >> 9) & 15;
    int nt   = idx >> 13;
    int n = nt*16 + (lane & 15);
    int k = kt*32 + (lane >> 4)*8 + j;
    Wp[idx] = (f16)Wout[n*512 + k];
}

__global__ void bias_sum(const float* __restrict__ a1, const float* __restrict__ b1,
                         const float* __restrict__ a2, const float* __restrict__ b2,
                         float* __restrict__ s1, float* __restrict__ s2) {
    int i = blockIdx.x * 256 + threadIdx.x;
    if (i >= 2048) return;
    s1[i] = a1[i] + b1[i];
    s2[i] = a2[i] + b2[i];
}

// ---------------- persistent self-timed kernel ----------------
// R10 = R9 tagged-word dataflow +
//  (1) L2's two serial tail polls merged into one interleaved poll (1 RT not 2);
//  (2) register c-state + shuffle-publish (no HB/CC LDS, one less barrier);
//  (3) cached look-ahead back-pressure checks (tid0 probes 4 ahead, skips most RTs).
__global__ __launch_bounds__(512, 1) void lstm_persist(
    const float* __restrict__ x,
    const f16*  __restrict__ W1p,
    const f16*  __restrict__ W2p,
    const f16*  __restrict__ Wop,
    const float* __restrict__ bs1,
    const float* __restrict__ bs2,
    const float* __restrict__ bout,
    u64*  __restrict__ h1w,     // [8][2][6144] tagged words
    u64*  __restrict__ h2w,     // [8][2][6144]
    float* __restrict__ y,
    u32*  __restrict__ arr2,    // [2][1024]
    u32*  __restrict__ arrH)    // [2][1024]
{
    __shared__ __align__(16) char smem[158720];
    float* RED = (float*)(smem + RED_OFF);

    const int wg   = blockIdx.x;
    const int tid  = threadIdx.x;
    const int lane = tid & 63;
    const int w    = tid >> 6;
    const int col  = lane & 15;
    const int quad = lane >> 4;

    // staging LDS offsets for this thread's 12 words
    int soff[12];
    #pragma unroll
    for (int i = 0; i < 12; ++i) {
        const int ww = i*512 + tid;
        const int jt_ = ww / 192, rr = ww - jt_*192;
        soff[i] = WB(jt_, rr/6, rr%6);
    }

    if (wg < 64) {
        // ================= layer 1 =================
        const int jt = wg & 31, bhalf = wg >> 5;
        const int gp = w & 1, kq = w >> 1;
        half8 wrx[2];
        half8 wrh[2][4];
        if (kq < 2) {
            #pragma unroll
            for (int gi = 0; gi < 2; ++gi)
                wrx[gi] = *(const half8*)(W1p + ((size_t)(((gp*2+gi)*32 + jt)*18 + kq)*64 + lane)*8);
        }
        #pragma unroll
        for (int gi = 0; gi < 2; ++gi)
            #pragma unroll
            for (int k = 0; k < 4; ++k) {
                const int kt = 2 + kq*4 + k;
                wrh[gi][k] = *(const half8*)(W1p + ((size_t)(((gp*2+gi)*32 + jt)*18 + kt)*64 + lane)*8);
            }
        float bsr[4];
        #pragma unroll
        for (int g = 0; g < 4; ++g) bsr[g] = bs1[g*512 + jt*16 + (tid & 15)];
        float creg = 0.f;
        int okA2 = -1;

        u32* a2 = arr2 + bhalf*1024;

        // prologue: x_0 + h1[-1] (slot 7, tag 0 = zeroed buffer)
        {
            const int lb = tid >> 4, kc4 = tid & 15;
            const float* src = x + ((size_t)(bhalf*32 + lb)*T_ + 0)*(size_t)IN_ + ((kc4 ^ (lb & 7)) * 4);
            *(float4*)(smem + XS_OFF + tid*16) = *(const float4*)src;
        }
        stage_poll(smem, H1W_OFF, h1w + (size_t)(7*2 + bhalf)*NWORD, 0u, tid, soff);
        __syncthreads();

        for (int t = 0; t < T_; ++t) {
            floatx4 acc[2][2] = {{{0.f,0.f,0.f,0.f},{0.f,0.f,0.f,0.f}},
                                 {{0.f,0.f,0.f,0.f},{0.f,0.f,0.f,0.f}}};
            #pragma unroll
            for (int m = 0; m < 2; ++m) {
                const int lb_a = m*16 + col, sw = lb_a & 7;
                if (kq < 2) {   // x-part: this kq's 32-col tile
                    const int fg = kq*8 + quad*2;
                    float4 u = *(const float4*)(smem + XS_OFF + ((size_t)lb_a*16 + (fg ^ sw))*16);
                    float4 v = *(const float4*)(smem + XS_OFF + ((size_t)lb_a*16 + ((fg+1) ^ sw))*16);
                    half8 a = (half8){(f16)u.x,(f16)u.y,(f16)u.z,(f16)u.w,
                                      (f16)v.x,(f16)v.y,(f16)v.z,(f16)v.w};
                    acc[0][m] = MFMA16(a, wrx[0], acc[0][m]);
                    acc[1][m] = MFMA16(a, wrx[1], acc[1][m]);
                }
                #pragma unroll
                for (int k = 0; k < 4; ++k) {
                    const int kc = kq*16 + k*4 + quad;
                    half8 a = frag_pk(smem + H1W_OFF + WB(kc>>1, lb_a, (kc&1)*3));
                    acc[0][m] = MFMA16(a, wrh[0][k], acc[0][m]);
                    acc[1][m] = MFMA16(a, wrh[1][k], acc[1][m]);
                }
            }
            #pragma unroll
            for (int gi = 0; gi < 2; ++gi) {
                const int g = gp*2 + gi;
                #pragma unroll
                for (int m = 0; m < 2; ++m)
                    #pragma unroll
                    for (int r = 0; r < 4; ++r)
                        RED[kq*2048 + g*512 + (m*16 + quad*4 + r)*16 + col] = acc[gi][m][r];
            }
            __syncthreads();
            {   // 4-way kq sum + pointwise (c in reg) + shuffle-publish h1[t]
                float gt[4];
                #pragma unroll
                for (int g = 0; g < 4; ++g)
                    gt[g] = RED[       g*512 + tid] + RED[2048 + g*512 + tid]
                          + RED[4096 + g*512 + tid] + RED[6144 + g*512 + tid] + bsr[g];
                const float i_ = sigmoidf_(gt[0]);
                const float f_ = sigmoidf_(gt[1]);
                const float g_ = tanhf_(gt[2]);
                const float o_ = sigmoidf_(gt[3]);
                const float cn = f_ * creg + i_ * g_;
                creg = cn;
                shuf_publish(h1w + (size_t)((t & 7)*2 + bhalf)*NWORD + jt*192,
                             tid, t + 1, o_ * tanhf_(cn));
            }
            // back-pressure (cached look-ahead): L2 done reading h1[t+1-8]
            if (tid == 0 && t + 1 < T_ && t + 1 >= SLOTS)
                cached_wait(a2, t + 1 - SLOTS, 32u, &okA2);
            if (t + 1 < T_) {
                {   // stage x_{t+1}
                    const int lb = tid >> 4, kc4 = tid & 15;
                    const float* src = x + ((size_t)(bhalf*32 + lb)*T_ + (t+1))*(size_t)IN_ + ((kc4 ^ (lb & 7)) * 4);
                    *(float4*)(smem + XS_OFF + tid*16) = *(const float4*)src;
                }
                // stage h1[t] (just published by self + 31 peers): the poll IS the sync
                stage_poll(smem, H1W_OFF, h1w + (size_t)((t & 7)*2 + bhalf)*NWORD,
                           (u32)(t + 1), tid, soff);
            }
            __syncthreads();   // staged data visible to all waves
        }
    } else if (wg < 128) {
        // ================= layer 2 =================
        const int v = wg - 64;
        const int jt = v & 31, bhalf = v >> 5;
        const int gp = w & 1, kq = w >> 1;
        half8 wrA[2][4], wrB[2][4];
        #pragma unroll
        for (int gi = 0; gi < 2; ++gi)
            #pragma unroll
            for (int k = 0; k < 4; ++k) {
                const int ktA = kq*4 + k;        // h1 half (K 0..511)
                const int ktB = 16 + kq*4 + k;   // h2 half (K 512..1023)
                wrA[gi][k] = *(const half8*)(W2p + ((size_t)(((gp*2+gi)*32 + jt)*32 + ktA)*64 + lane)*8);
                wrB[gi][k] = *(const half8*)(W2p + ((size_t)(((gp*2+gi)*32 + jt)*32 + ktB)*64 + lane)*8);
            }
        float bsr[4];
        #pragma unroll
        for (int g = 0; g < 4; ++g) bsr[g] = bs2[g*512 + jt*16 + (tid & 15)];
        float creg = 0.f;
        int okAH = -1;

        u32* a2 = arr2 + bhalf*1024;
        u32* aH = arrH + bhalf*1024;

        // prologue: h1[0] (tag 1) + h2[-1] (slot 7, tag 0) -- one interleaved poll
        stage_poll2(smem, h1w + (size_t)(0*2 + bhalf)*NWORD, 1u,
                          h2w + (size_t)(7*2 + bhalf)*NWORD, 0u, tid, soff);
        __syncthreads();

        for (int t2 = 0; t2 < T_; ++t2) {
            floatx4 acc[2][2] = {{{0.f,0.f,0.f,0.f},{0.f,0.f,0.f,0.f}},
                                 {{0.f,0.f,0.f,0.f},{0.f,0.f,0.f,0.f}}};
            #pragma unroll
            for (int m = 0; m < 2; ++m) {   // pass A (h1[t2])
                const int lb_a = m*16 + col;
                #pragma unroll
                for (int k = 0; k < 4; ++k) {
                    const int kc = kq*16 + k*4 + quad;
                    half8 a = frag_pk(smem + H1W_OFF + WB(kc>>1, lb_a, (kc&1)*3));
                    acc[0][m] = MFMA16(a, wrA[0][k], acc[0][m]);
                    acc[1][m] = MFMA16(a, wrA[1][k], acc[1][m]);
                }
            }
            #pragma unroll
            for (int m = 0; m < 2; ++m) {   // pass B (h2[t2-1])
                const int lb_a = m*16 + col;
                #pragma unroll
                for (int k = 0; k < 4; ++k) {
                    const int kc = kq*16 + k*4 + quad;
                    half8 a = frag_pk(smem + H2W_OFF + WB(kc>>1, lb_a, (kc&1)*3));
                    acc[0][m] = MFMA16(a, wrB[0][k], acc[0][m]);
                    acc[1][m] = MFMA16(a, wrB[1][k], acc[1][m]);
                }
            }
            #pragma unroll
            for (int gi = 0; gi < 2; ++gi) {
                const int g = gp*2 + gi;
                #pragma unroll
                for (int m = 0; m < 2; ++m)
                    #pragma unroll
                    for (int r = 0; r < 4; ++r)
                        RED[kq*2048 + g*512 + (m*16 + quad*4 + r)*16 + col] = acc[gi][m][r];
            }
            __syncthreads();
            {   // 4-way kq sum + pointwise (c in reg) + shuffle-publish h2[t2]
                float gt[4];
                #pragma unroll
                for (int g = 0; g < 4; ++g)
                    gt[g] = RED[       g*512 + tid] + RED[2048 + g*512 + tid]
                          + RED[4096 + g*512 + tid] + RED[6144 + g*512 + tid] + bsr[g];
                const float i_ = sigmoidf_(gt[0]);
                const float f_ = sigmoidf_(gt[1]);
                const float g_ = tanhf_(gt[2]);
                const float o_ = sigmoidf_(gt[3]);
                const float cn = f_ * creg + i_ * g_;
                creg = cn;
                shuf_publish(h2w + (size_t)((t2 & 7)*2 + bhalf)*NWORD + jt*192,
                             tid, t2 + 1, o_ * tanhf_(cn));
            }
            // release L1's slot guard (done reading h1[t2] from LDS long ago)
            if (tid == 0) flag_add(a2 + t2);
            // back-pressure (cached look-ahead): head staged h2[t2+1-8]
            if (tid == 0 && t2 + 1 < T_ && t2 + 1 >= SLOTS)
                cached_wait(aH, t2 + 1 - SLOTS, 1u, &okAH);
            if (t2 + 1 < T_) {
                // ONE interleaved poll: h1[t2+1] (tag t2+2) + h2[t2] (tag t2+1)
                stage_poll2(smem, h1w + (size_t)(((t2+1) & 7)*2 + bhalf)*NWORD, (u32)(t2 + 2),
                                  h2w + (size_t)((t2 & 7)*2 + bhalf)*NWORD,     (u32)(t2 + 1),
                            tid, soff);
            }
            __syncthreads();
        }
    } else {
        // ================= head =================
        const int bhalf = wg - 128;
        const int nt = w & 3, kh = w >> 2;
        half8 wr[8];
        #pragma unroll
        for (int k = 0; k < 8; ++k) {
            const int kt = kh*8 + k;
            wr[k] = *(const half8*)(Wop + ((size_t)(nt*16 + kt)*64 + lane)*8);
        }
        const float boutr = bout[nt*16 + col];
        u32* aH = arrH + bhalf*1024;
        const int lb0 = col, lb1 = 16 + col;

        // prologue: stage h2[0]
        stage_poll(smem, H1W_OFF, h2w + (size_t)(0*2 + bhalf)*NWORD, 1u, tid, soff);
        __syncthreads();
        if (tid == 0) flag_add(aH + 0);

        for (int t3 = 0; t3 < T_; ++t3) {
            floatx4 acc0 = {0.f,0.f,0.f,0.f}, acc1 = {0.f,0.f,0.f,0.f};
            #pragma unroll
            for (int k = 0; k < 8; ++k) {
                const int kc = (kh*8 + k)*4 + quad;
                half8 a0  = frag_pk(smem + H1W_OFF + WB(kc>>1, lb0, (kc&1)*3));
                half8 a1v = frag_pk(smem + H1W_OFF + WB(kc>>1, lb1, (kc&1)*3));
                acc0 = MFMA16(a0,  wr[k], acc0);
                acc1 = MFMA16(a1v, wr[k], acc1);
            }
            if (kh == 1) {
                #pragma unroll
                for (int r = 0; r < 4; ++r) {
                    RED[(nt*2+0)*256 + (quad*4 + r)*16 + col] = acc0[r];
                    RED[(nt*2+1)*256 + (quad*4 + r)*16 + col] = acc1[r];
                }
            }
            __syncthreads();
            if (kh == 0) {
                #pragma unroll
                for (int r = 0; r < 4; ++r) {
                    const float v0 = acc0[r] + RED[(nt*2+0)*256 + (quad*4 + r)*16 + col] + boutr;
                    const float v1 = acc1[r] + RED[(nt*2+1)*256 + (quad*4 + r)*16 + col] + boutr;
                    const int b0 = bhalf*32 +  0 + quad*4 + r;
                    const int b1 = bhalf*32 + 16 + quad*4 + r;
                    y[((size_t)b0*T_ + t3)*OUT_ + nt*16 + col] = v0;
                    y[((size_t)b1*T_ + t3)*OUT_ + nt*16 + col] = v1;
                }
            }
            __syncthreads();   // RED reuse
            if (t3 + 1 < T_) {
                stage_poll(smem, H1W_OFF, h2w + (size_t)(((t3+1) & 7)*2 + bhalf)*NWORD,
                           (u32)(t3 + 2), tid, soff);
                __syncthreads();               // staging complete
                if (tid == 0) flag_add(aH + (t3 + 1));   // release L2's slot guard
            }
        }
    }
}

// ---------------- launch ----------------
extern "C" void kernel_launch(void* const* d_in, const int* in_sizes, int n_in,
                              void* d_out, int out_size, void* d_ws, size_t ws_size,
                              hipStream_t stream) {
    const float* x    = (const float*)d_in[0];
    const float* Wih1 = (const float*)d_in[1];
    const float* Whh1 = (const float*)d_in[2];
    const float* bih1 = (const float*)d_in[3];
    const float* bhh1 = (const float*)d_in[4];
    const float* Wih2 = (const float*)d_in[5];
    const float* Whh2 = (const float*)d_in[6];
    const float* bih2 = (const float*)d_in[7];
    const float* bhh2 = (const float*)d_in[8];
    const float* Wout = (const float*)d_in[9];
    const float* bout = (const float*)d_in[10];
    float* y = (float*)d_out;

    char* ws = (char*)d_ws;
    f16*   W1p   = (f16*)(ws + 0);           // 2,359,296 B
    f16*   W2p   = (f16*)(ws + 2359296);     // 4,194,304 B
    f16*   Wop   = (f16*)(ws + 6553600);     //    65,536 B
    float* bs1   = (float*)(ws + 6619136);   //     8,192 B
    float* bs2   = (float*)(ws + 6627328);   //     8,192 B
    u64*   h1w   = (u64*)(ws + 6635520);     //   786,432 B (8 slots x 2 bh x 6144 words)
    u64*   h2w   = (u64*)(ws + 7421952);     //   786,432 B
    u32*   arr2  = (u32*)(ws + 8208384);     //     8,192 B
    u32*   arrH  = (u32*)(ws + 8216576);     //     8,192 B

    // zero tagged-word buffers (tag 0 = step -1 state) + back-pressure counters
    hipMemsetAsync(ws + 6635520, 0, 1589248, stream);

    pack_w1<<<4608, 256, 0, stream>>>(Wih1, Whh1, W1p);
    pack_w2<<<8192, 256, 0, stream>>>(Wih2, Whh2, W2p);
    pack_wo<<<128, 256, 0, stream>>>(Wout, Wop);
    bias_sum<<<8, 256, 0, stream>>>(bih1, bhh1, bih2, bhh2, bs1, bs2);

    lstm_persist<<<NWG, 512, 0, stream>>>(x, W1p, W2p, Wop, bs1, bs2, bout,
                                          h1w, h2w, y, arr2, arrH);
}

// Round 6
// 5931.307 us; speedup vs baseline: 1.1982x; 1.1982x over previous
//
#include <hip/hip_runtime.h>

#define B_    64
#define T_    1024
#define IN_   64
#define H_    512
#define OUT_  64
#define SLOTS 8
#define NWG   130
#define NWORD 6144      // words per (bhalf, slot): 32 jt * 32 rows * 6 words

typedef _Float16 f16;
typedef _Float16 half8 __attribute__((ext_vector_type(8)));
typedef float    floatx4 __attribute__((ext_vector_type(4)));
typedef unsigned int u32;
typedef unsigned short u16;
typedef unsigned long long u64;

#define MFMA16(a,b,c) __builtin_amdgcn_mfma_f32_16x16x32_f16((a),(b),(c),0,0,0)

// LDS layout (158720 B, 1 WG/CU)
// H1W/H2W hold RAW tagged words [jt][row][7] (row stride 7 u64 = 56B -> 16-bank spread)
#define XS_OFF   0        // 8KB: L1 x-stage (dense fp32, swizzled as R5)
#define HB_OFF   8192     // 1KB: pointwise h output (f16[512])
#define CC_OFF   9216     // 2KB: c-state
#define RED_OFF  11264    // 32KB: 4 kq-regions x 8KB partial-sum
#define H1W_OFF  44032    // 57344: packed h words (h1 for L1/L2; h2 for head)
#define H2W_OFF  101376   // 57344: packed h2 words (L2 pass B)

__device__ __forceinline__ float sigmoidf_(float x) {
    return 1.0f / (1.0f + __expf(-x));
}
__device__ __forceinline__ float tanhf_(float x) {
    float ax = fabsf(x);
    float e  = __expf(-2.0f * ax);
    float t  = (1.0f - e) / (1.0f + e);
    return x >= 0.0f ? t : -t;
}

// Flags: agent-scope RMW + agent-scope poll (proven R2/R5). Back-pressure edges only.
__device__ __forceinline__ void wait_ge(u32* p, u32 v) {
    while (__hip_atomic_load(p, __ATOMIC_RELAXED, __HIP_MEMORY_SCOPE_AGENT) < v)
        __builtin_amdgcn_s_sleep(1);
}
__device__ __forceinline__ void flag_add(u32* p) {
    __hip_atomic_fetch_add(p, 1u, __ATOMIC_RELAXED, __HIP_MEMORY_SCOPE_AGENT);
}
// Tagged-word publish: relaxed system-scope atomic store. Tag is IN the word ->
// no ordering vs anything else is needed; word is self-validating.
__device__ __forceinline__ void astore8w(u64* p, u64 v) {
    __hip_atomic_store(p, v, __ATOMIC_RELAXED, __HIP_MEMORY_SCOPE_SYSTEM);
}
__device__ __forceinline__ u64 aload8w(const u64* p) {
    return __hip_atomic_load(p, __ATOMIC_RELAXED, __HIP_MEMORY_SCOPE_SYSTEM);
}

// Poll-stage ONE 49KB tagged buffer (6144 words) into LDS raw-word layout.
// Each thread owns 12 lane-coalesced words; re-loads all 12 per round (branch-free
// load batch), commits those whose tag matches. soff[i] precomputed per thread.
__device__ __forceinline__ void stage_poll(char* smem, int ldsOff, const u64* g,
                                           u32 exp, int tid, const int* soff) {
    u32 pend = 0xFFFu;
    do {
        u64 vv[12];
        #pragma unroll
        for (int i = 0; i < 12; ++i)
            vv[i] = aload8w(g + i*512 + tid);
        #pragma unroll
        for (int i = 0; i < 12; ++i) {
            if ((pend & (1u << i)) && (u32)(vv[i] >> 48) == exp) {
                *(u64*)(smem + ldsOff + soff[i]) = vv[i];
                pend &= ~(1u << i);
            }
        }
        if (pend) __builtin_amdgcn_s_sleep(1);
    } while (pend);
}

// Poll-stage TWO tagged buffers with INTERLEAVED loads (24 in flight): one MALL
// round trip covers both when satisfied, vs two serial RTs. (R11's single change)
__device__ __forceinline__ void stage_poll2(char* smem, const u64* g1, u32 e1,
                                            const u64* g2, u32 e2,
                                            int tid, const int* soff) {
    u32 p1 = 0xFFFu, p2 = 0xFFFu;
    do {
        u64 v1[12], v2[12];
        #pragma unroll
        for (int i = 0; i < 12; ++i) {
            v2[i] = aload8w(g2 + i*512 + tid);   // h2 first: the likely-pending one
            v1[i] = aload8w(g1 + i*512 + tid);
        }
        #pragma unroll
        for (int i = 0; i < 12; ++i) {
            if ((p2 & (1u << i)) && (u32)(v2[i] >> 48) == e2) {
                *(u64*)(smem + H2W_OFF + soff[i]) = v2[i];
                p2 &= ~(1u << i);
            }
            if ((p1 & (1u << i)) && (u32)(v1[i] >> 48) == e1) {
                *(u64*)(smem + H1W_OFF + soff[i]) = v1[i];
                p1 &= ~(1u << i);
            }
        }
        if (p1 | p2) __builtin_amdgcn_s_sleep(1);
    } while (p1 | p2);
}

// Build a half8 fragment (8 consecutive k-values) from 3 packed LDS words.
__device__ __forceinline__ half8 frag_pk(const char* p) {
    const u64* q = (const u64*)p;
    u64 w0 = q[0], w1 = q[1], w2 = q[2];
    u32 b = (u32)(w0 >> 32), c = (u32)w1, d = (u32)(w1 >> 32);
    union { u32 u[4]; half8 h; } U;
    U.u[0] = (u32)w0;
    U.u[1] = (b & 0xffffu) | (c << 16);
    U.u[2] = (c >> 16) | (d << 16);
    U.u[3] = (u32)w2;
    return U.h;
}
// LDS byte offset of word (jt, row, wi): ((jt*32+row)*7 + wi)*8
#define WB(jt,row,wi) (((jt)*224 + (row)*7 + (wi)) * 8)

// ---------------- prep kernels (weights -> fp16 fragment-linear) ----------------
__global__ void pack_w1(const float* __restrict__ Wih, const float* __restrict__ Whh,
                        f16* __restrict__ Wp) {
    int idx = blockIdx.x * 256 + threadIdx.x;
    if (idx >= 4*32*18*512) return;
    int j    = idx & 7;
    int lane = (idx >> 3) & 63;
    int kt   = (idx >> 9) % 18;
    int r    = (idx >> 9) / 18;
    int jt   = r & 31;
    int g    = r >> 5;
    int n = g*512 + jt*16 + (lane & 15);
    int k = kt*32 + (lane >> 4)*8 + j;
    float v = (k < 64) ? Wih[n*64 + k] : Whh[n*512 + (k - 64)];
    Wp[idx] = (f16)v;
}

__global__ void pack_w2(const float* __restrict__ Wih, const float* __restrict__ Whh,
                        f16* __restrict__ Wp) {
    int idx = blockIdx.x * 256 + threadIdx.x;
    if (idx >= 4*32*32*512) return;
    int j    = idx & 7;
    int lane = (idx >> 3) & 63;
    int kt   = (idx >> 9) & 31;
    int r    = idx >> 14;
    int jt   = r & 31;
    int g    = r >> 5;
    int n = g*512 + jt*16 + (lane & 15);
    int k = kt*32 + (lane >> 4)*8 + j;
    float v = (k < 512) ? Wih[n*512 + k] : Whh[n*512 + (k - 512)];
    Wp[idx] = (f16)v;
}

__global__ void pack_wo(const float* __restrict__ Wout, f16* __restrict__ Wp) {
    int idx = blockIdx.x * 256 + threadIdx.x;
    if (idx >= 4*16*512) return;
    int j    = idx & 7;
    int lane = (idx >> 3) & 63;
    int kt   = (idx >> 9) & 15;
    int nt   = idx >> 13;
    int n = nt*16 + (lane & 15);
    int k = kt*32 + (lane >> 4)*8 + j;
    Wp[idx] = (f16)Wout[n*512 + k];
}

__global__ void bias_sum(const float* __restrict__ a1, const float* __restrict__ b1,
                         const float* __restrict__ a2, const float* __restrict__ b2,
                         float* __restrict__ s1, float* __restrict__ s2) {
    int i = blockIdx.x * 256 + threadIdx.x;
    if (i >= 2048) return;
    s1[i] = a1[i] + b1[i];
    s2[i] = a2[i] + b2[i];
}

// ---------------- persistent self-timed kernel ----------------
// R11 = R9 verbatim (best: 4754 us) + ONE change: L2's two serial tail polls
// (h1[t2+1] then h2[t2]) merged into one interleaved poll (stage_poll2), saving
// one MALL round trip per L2 period. R10's cached_wait and shuffle-publish are
// REVERTED (cached_wait's look-ahead probe always fails at steady state because
// both guards run pinned at the full 8-slot lead -> it ADDED one RT per step).
__global__ __launch_bounds__(512, 1) void lstm_persist(
    const float* __restrict__ x,
    const f16*  __restrict__ W1p,
    const f16*  __restrict__ W2p,
    const f16*  __restrict__ Wop,
    const float* __restrict__ bs1,
    const float* __restrict__ bs2,
    const float* __restrict__ bout,
    u64*  __restrict__ h1w,     // [8][2][6144] tagged words
    u64*  __restrict__ h2w,     // [8][2][6144]
    float* __restrict__ y,
    u32*  __restrict__ arr2,    // [2][1024]
    u32*  __restrict__ arrH)    // [2][1024]
{
    __shared__ __align__(16) char smem[158720];
    float* RED = (float*)(smem + RED_OFF);
    float* CC  = (float*)(smem + CC_OFF);

    const int wg   = blockIdx.x;
    const int tid  = threadIdx.x;
    const int lane = tid & 63;
    const int w    = tid >> 6;
    const int col  = lane & 15;
    const int quad = lane >> 4;

    // staging LDS offsets for this thread's 12 words
    int soff[12];
    #pragma unroll
    for (int i = 0; i < 12; ++i) {
        const int ww = i*512 + tid;
        const int jt_ = ww / 192, rr = ww - jt_*192;
        soff[i] = WB(jt_, rr/6, rr%6);
    }
    // publisher params (valid for tid<192): word tid = r*6 + i of own slice
    const int pr  = tid / 6, pi = tid - pr*6;
    const int pj  = pi % 3;
    const int pc0 = pr*16 + (pi/3)*8 + pj*3;   // first col of this word
    const u16* hb = (const u16*)(smem + HB_OFF);

    if (wg < 64) {
        // ================= layer 1 =================
        const int jt = wg & 31, bhalf = wg >> 5;
        const int gp = w & 1, kq = w >> 1;
        half8 wrx[2];
        half8 wrh[2][4];
        if (kq < 2) {
            #pragma unroll
            for (int gi = 0; gi < 2; ++gi)
                wrx[gi] = *(const half8*)(W1p + ((size_t)(((gp*2+gi)*32 + jt)*18 + kq)*64 + lane)*8);
        }
        #pragma unroll
        for (int gi = 0; gi < 2; ++gi)
            #pragma unroll
            for (int k = 0; k < 4; ++k) {
                const int kt = 2 + kq*4 + k;
                wrh[gi][k] = *(const half8*)(W1p + ((size_t)(((gp*2+gi)*32 + jt)*18 + kt)*64 + lane)*8);
            }
        float bsr[4];
        #pragma unroll
        for (int g = 0; g < 4; ++g) bsr[g] = bs1[g*512 + jt*16 + (tid & 15)];
        CC[tid] = 0.f;

        u32* a2 = arr2 + bhalf*1024;

        // prologue: x_0 + h1[-1] (slot 7, tag 0 = zeroed buffer)
        {
            const int lb = tid >> 4, kc4 = tid & 15;
            const float* src = x + ((size_t)(bhalf*32 + lb)*T_ + 0)*(size_t)IN_ + ((kc4 ^ (lb & 7)) * 4);
            *(float4*)(smem + XS_OFF + tid*16) = *(const float4*)src;
        }
        stage_poll(smem, H1W_OFF, h1w + (size_t)(7*2 + bhalf)*NWORD, 0u, tid, soff);
        __syncthreads();

        for (int t = 0; t < T_; ++t) {
            floatx4 acc[2][2] = {{{0.f,0.f,0.f,0.f},{0.f,0.f,0.f,0.f}},
                                 {{0.f,0.f,0.f,0.f},{0.f,0.f,0.f,0.f}}};
            #pragma unroll
            for (int m = 0; m < 2; ++m) {
                const int lb_a = m*16 + col, sw = lb_a & 7;
                if (kq < 2) {   // x-part: this kq's 32-col tile
                    const int fg = kq*8 + quad*2;
                    float4 u = *(const float4*)(smem + XS_OFF + ((size_t)lb_a*16 + (fg ^ sw))*16);
                    float4 v = *(const float4*)(smem + XS_OFF + ((size_t)lb_a*16 + ((fg+1) ^ sw))*16);
                    half8 a = (half8){(f16)u.x,(f16)u.y,(f16)u.z,(f16)u.w,
                                      (f16)v.x,(f16)v.y,(f16)v.z,(f16)v.w};
                    acc[0][m] = MFMA16(a, wrx[0], acc[0][m]);
                    acc[1][m] = MFMA16(a, wrx[1], acc[1][m]);
                }
                #pragma unroll
                for (int k = 0; k < 4; ++k) {
                    const int kc = kq*16 + k*4 + quad;
                    half8 a = frag_pk(smem + H1W_OFF + WB(kc>>1, lb_a, (kc&1)*3));
                    acc[0][m] = MFMA16(a, wrh[0][k], acc[0][m]);
                    acc[1][m] = MFMA16(a, wrh[1][k], acc[1][m]);
                }
            }
            #pragma unroll
            for (int gi = 0; gi < 2; ++gi) {
                const int g = gp*2 + gi;
                #pragma unroll
                for (int m = 0; m < 2; ++m)
                    #pragma unroll
                    for (int r = 0; r < 4; ++r)
                        RED[kq*2048 + g*512 + (m*16 + quad*4 + r)*16 + col] = acc[gi][m][r];
            }
            __syncthreads();
            {   // 4-way kq sum + pointwise -> HB
                float gt[4];
                #pragma unroll
                for (int g = 0; g < 4; ++g)
                    gt[g] = RED[       g*512 + tid] + RED[2048 + g*512 + tid]
                          + RED[4096 + g*512 + tid] + RED[6144 + g*512 + tid] + bsr[g];
                const float i_ = sigmoidf_(gt[0]);
                const float f_ = sigmoidf_(gt[1]);
                const float g_ = tanhf_(gt[2]);
                const float o_ = sigmoidf_(gt[3]);
                const float cn = f_ * CC[tid] + i_ * g_;
                CC[tid] = cn;
                ((f16*)(smem + HB_OFF))[tid] = (f16)(o_ * tanhf_(cn));
            }
            __syncthreads();
            // publish h1[t] (tagged words, one-way stores) -- earliest possible
            if (tid < 192) {
                u64 wv = (u64)hb[pc0] | ((u64)hb[pc0+1] << 16)
                       | ((pj < 2) ? ((u64)hb[pc0+2] << 32) : 0)
                       | ((u64)(u32)(t + 1) << 48);
                astore8w(h1w + (size_t)((t & 7)*2 + bhalf)*NWORD + jt*192 + tid, wv);
            }
            // back-pressure for NEXT publish (slot reuse): L2 done reading h1[t-7]
            if (tid == 0 && t + 1 < T_ && t + 1 >= SLOTS)
                wait_ge(a2 + (t + 1 - SLOTS), 32u);
            if (t + 1 < T_) {
                {   // stage x_{t+1} (plain loads; XS free after MFMA barriers)
                    const int lb = tid >> 4, kc4 = tid & 15;
                    const float* src = x + ((size_t)(bhalf*32 + lb)*T_ + (t+1))*(size_t)IN_ + ((kc4 ^ (lb & 7)) * 4);
                    *(float4*)(smem + XS_OFF + tid*16) = *(const float4*)src;
                }
                // stage h1[t] (just published by self + 31 peers): the poll IS the sync
                stage_poll(smem, H1W_OFF, h1w + (size_t)((t & 7)*2 + bhalf)*NWORD,
                           (u32)(t + 1), tid, soff);
            }
            __syncthreads();   // staged data ready; store-acks drain hidden behind poll
        }
    } else if (wg < 128) {
        // ================= layer 2 =================
        const int v = wg - 64;
        const int jt = v & 31, bhalf = v >> 5;
        const int gp = w & 1, kq = w >> 1;
        half8 wrA[2][4], wrB[2][4];
        #pragma unroll
        for (int gi = 0; gi < 2; ++gi)
            #pragma unroll
            for (int k = 0; k < 4; ++k) {
                const int ktA = kq*4 + k;        // h1 half (K 0..511)
                const int ktB = 16 + kq*4 + k;   // h2 half (K 512..1023)
                wrA[gi][k] = *(const half8*)(W2p + ((size_t)(((gp*2+gi)*32 + jt)*32 + ktA)*64 + lane)*8);
                wrB[gi][k] = *(const half8*)(W2p + ((size_t)(((gp*2+gi)*32 + jt)*32 + ktB)*64 + lane)*8);
            }
        float bsr[4];
        #pragma unroll
        for (int g = 0; g < 4; ++g) bsr[g] = bs2[g*512 + jt*16 + (tid & 15)];
        CC[tid] = 0.f;

        u32* a2 = arr2 + bhalf*1024;
        u32* aH = arrH + bhalf*1024;

        // prologue: h1[0] (tag 1) + h2[-1] (slot 7, tag 0) -- one interleaved poll
        stage_poll2(smem, h1w + (size_t)(0*2 + bhalf)*NWORD, 1u,
                          h2w + (size_t)(7*2 + bhalf)*NWORD, 0u, tid, soff);
        __syncthreads();

        for (int t2 = 0; t2 < T_; ++t2) {
            floatx4 acc[2][2] = {{{0.f,0.f,0.f,0.f},{0.f,0.f,0.f,0.f}},
                                 {{0.f,0.f,0.f,0.f},{0.f,0.f,0.f,0.f}}};
            #pragma unroll
            for (int m = 0; m < 2; ++m) {   // pass A (h1[t2])
                const int lb_a = m*16 + col;
                #pragma unroll
                for (int k = 0; k < 4; ++k) {
                    const int kc = kq*16 + k*4 + quad;
                    half8 a = frag_pk(smem + H1W_OFF + WB(kc>>1, lb_a, (kc&1)*3));
                    acc[0][m] = MFMA16(a, wrA[0][k], acc[0][m]);
                    acc[1][m] = MFMA16(a, wrA[1][k], acc[1][m]);
                }
            }
            #pragma unroll
            for (int m = 0; m < 2; ++m) {   // pass B (h2[t2-1])
                const int lb_a = m*16 + col;
                #pragma unroll
                for (int k = 0; k < 4; ++k) {
                    const int kc = kq*16 + k*4 + quad;
                    half8 a = frag_pk(smem + H2W_OFF + WB(kc>>1, lb_a, (kc&1)*3));
                    acc[0][m] = MFMA16(a, wrB[0][k], acc[0][m]);
                    acc[1][m] = MFMA16(a, wrB[1][k], acc[1][m]);
                }
            }
            #pragma unroll
            for (int gi = 0; gi < 2; ++gi) {
                const int g = gp*2 + gi;
                #pragma unroll
                for (int m = 0; m < 2; ++m)
                    #pragma unroll
                    for (int r = 0; r < 4; ++r)
                        RED[kq*2048 + g*512 + (m*16 + quad*4 + r)*16 + col] = acc[gi][m][r];
            }
            __syncthreads();
            {   // 4-way kq sum + pointwise -> HB
                float gt[4];
                #pragma unroll
                for (int g = 0; g < 4; ++g)
                    gt[g] = RED[       g*512 + tid] + RED[2048 + g*512 + tid]
                          + RED[4096 + g*512 + tid] + RED[6144 + g*512 + tid] + bsr[g];
                const float i_ = sigmoidf_(gt[0]);
                const float f_ = sigmoidf_(gt[1]);
                const float g_ = tanhf_(gt[2]);
                const float o_ = sigmoidf_(gt[3]);
                const float cn = f_ * CC[tid] + i_ * g_;
                CC[tid] = cn;
                ((f16*)(smem + HB_OFF))[tid] = (f16)(o_ * tanhf_(cn));
            }
            __syncthreads();
            // publish h2[t2] -- earliest possible, one-way stores
            if (tid < 192) {
                u64 wv = (u64)hb[pc0] | ((u64)hb[pc0+1] << 16)
                       | ((pj < 2) ? ((u64)hb[pc0+2] << 32) : 0)
                       | ((u64)(u32)(t2 + 1) << 48);
                astore8w(h2w + (size_t)((t2 & 7)*2 + bhalf)*NWORD + jt*192 + tid, wv);
            }
            // done reading h1[t2] & h2[t2-1]: release L1's slot guard
            if (tid == 0) flag_add(a2 + t2);
            // back-pressure for NEXT publish: head staged h2[t2-7]
            if (tid == 0 && t2 + 1 < T_ && t2 + 1 >= SLOTS)
                wait_ge(aH + (t2 + 1 - SLOTS), 1u);
            if (t2 + 1 < T_) {
                // ONE interleaved poll: h1[t2+1] (tag t2+2) + h2[t2] (tag t2+1)
                stage_poll2(smem, h1w + (size_t)(((t2+1) & 7)*2 + bhalf)*NWORD, (u32)(t2 + 2),
                                  h2w + (size_t)((t2 & 7)*2 + bhalf)*NWORD,     (u32)(t2 + 1),
                            tid, soff);
            }
            __syncthreads();
        }
    } else {
        // ================= head =================
        const int bhalf = wg - 128;
        const int nt = w & 3, kh = w >> 2;
        half8 wr[8];
        #pragma unroll
        for (int k = 0; k < 8; ++k) {
            const int kt = kh*8 + k;
            wr[k] = *(const half8*)(Wop + ((size_t)(nt*16 + kt)*64 + lane)*8);
        }
        const float boutr = bout[nt*16 + col];
        u32* aH = arrH + bhalf*1024;
        const int lb0 = col, lb1 = 16 + col;

        // prologue: stage h2[0]
        stage_poll(smem, H1W_OFF, h2w + (size_t)(0*2 + bhalf)*NWORD, 1u, tid, soff);
        __syncthreads();
        if (tid == 0) flag_add(aH + 0);

        for (int t3 = 0; t3 < T_; ++t3) {
            floatx4 acc0 = {0.f,0.f,0.f,0.f}, acc1 = {0.f,0.f,0.f,0.f};
            #pragma unroll
            for (int k = 0; k < 8; ++k) {
                const int kc = (kh*8 + k)*4 + quad;
                half8 a0  = frag_pk(smem + H1W_OFF + WB(kc>>1, lb0, (kc&1)*3));
                half8 a1v = frag_pk(smem + H1W_OFF + WB(kc>>1, lb1, (kc&1)*3));
                acc0 = MFMA16(a0,  wr[k], acc0);
                acc1 = MFMA16(a1v, wr[k], acc1);
            }
            if (kh == 1) {
                #pragma unroll
                for (int r = 0; r < 4; ++r) {
                    RED[(nt*2+0)*256 + (quad*4 + r)*16 + col] = acc0[r];
                    RED[(nt*2+1)*256 + (quad*4 + r)*16 + col] = acc1[r];
                }
            }
            __syncthreads();
            if (kh == 0) {
                #pragma unroll
                for (int r = 0; r < 4; ++r) {
                    const float v0 = acc0[r] + RED[(nt*2+0)*256 + (quad*4 + r)*16 + col] + boutr;
                    const float v1 = acc1[r] + RED[(nt*2+1)*256 + (quad*4 + r)*16 + col] + boutr;
                    const int b0 = bhalf*32 +  0 + quad*4 + r;
                    const int b1 = bhalf*32 + 16 + quad*4 + r;
                    y[((size_t)b0*T_ + t3)*OUT_ + nt*16 + col] = v0;
                    y[((size_t)b1*T_ + t3)*OUT_ + nt*16 + col] = v1;
                }
            }
            __syncthreads();   // RED reuse
            if (t3 + 1 < T_) {
                stage_poll(smem, H1W_OFF, h2w + (size_t)(((t3+1) & 7)*2 + bhalf)*NWORD,
                           (u32)(t3 + 2), tid, soff);
                __syncthreads();               // staging complete
                if (tid == 0) flag_add(aH + (t3 + 1));   // release L2's slot guard
            }
        }
    }
}

// ---------------- launch ----------------
extern "C" void kernel_launch(void* const* d_in, const int* in_sizes, int n_in,
                              void* d_out, int out_size, void* d_ws, size_t ws_size,
                              hipStream_t stream) {
    const float* x    = (const float*)d_in[0];
    const float* Wih1 = (const float*)d_in[1];
    const float* Whh1 = (const float*)d_in[2];
    const float* bih1 = (const float*)d_in[3];
    const float* bhh1 = (const float*)d_in[4];
    const float* Wih2 = (const float*)d_in[5];
    const float* Whh2 = (const float*)d_in[6];
    const float* bih2 = (const float*)d_in[7];
    const float* bhh2 = (const float*)d_in[8];
    const float* Wout = (const float*)d_in[9];
    const float* bout = (const float*)d_in[10];
    float* y = (float*)d_out;

    char* ws = (char*)d_ws;
    f16*   W1p   = (f16*)(ws + 0);           // 2,359,296 B
    f16*   W2p   = (f16*)(ws + 2359296);     // 4,194,304 B
    f16*   Wop   = (f16*)(ws + 6553600);     //    65,536 B
    float* bs1   = (float*)(ws + 6619136);   //     8,192 B
    float* bs2   = (float*)(ws + 6627328);   //     8,192 B
    u64*   h1w   = (u64*)(ws + 6635520);     //   786,432 B (8 slots x 2 bh x 6144 words)
    u64*   h2w   = (u64*)(ws + 7421952);     //   786,432 B
    u32*   arr2  = (u32*)(ws + 8208384);     //     8,192 B
    u32*   arrH  = (u32*)(ws + 8216576);     //     8,192 B

    // zero tagged-word buffers (tag 0 = step -1 state) + back-pressure counters
    hipMemsetAsync(ws + 6635520, 0, 1589248, stream);

    pack_w1<<<4608, 256, 0, stream>>>(Wih1, Whh1, W1p);
    pack_w2<<<8192, 256, 0, stream>>>(Wih2, Whh2, W2p);
    pack_wo<<<128, 256, 0, stream>>>(Wout, Wop);
    bias_sum<<<8, 256, 0, stream>>>(bih1, bhh1, bih2, bhh2, bs1, bs2);

    lstm_persist<<<NWG, 512, 0, stream>>>(x, W1p, W2p, Wop, bs1, bs2, bout,
                                          h1w, h2w, y, arr2, arrH);
}

// Round 8
// 4786.214 us; speedup vs baseline: 1.4849x; 1.2392x over previous
//
#include <hip/hip_runtime.h>

#define B_    64
#define T_    1024
#define IN_   64
#define H_    512
#define OUT_  64
#define SLOTS 8
#define NWG   130
#define NWORD 6144      // words per (bhalf, slot): 32 jt * 32 rows * 6 words

typedef _Float16 f16;
typedef _Float16 half8 __attribute__((ext_vector_type(8)));
typedef float    floatx4 __attribute__((ext_vector_type(4)));
typedef unsigned int u32;
typedef unsigned short u16;
typedef unsigned long long u64;

#define MFMA16(a,b,c) __builtin_amdgcn_mfma_f32_16x16x32_f16((a),(b),(c),0,0,0)

// LDS layout (158720 B, 1 WG/CU)
// H1W/H2W hold RAW tagged words [jt][row][7] (row stride 7 u64 = 56B -> 16-bank spread)
#define XS_OFF   0        // 8KB: L1 x-stage (dense fp32, swizzled as R5)
#define HB_OFF   8192     // 1KB: pointwise h output (f16[512])
#define CC_OFF   9216     // 2KB: c-state
#define RED_OFF  11264    // 32KB: 4 kq-regions x 8KB partial-sum
#define H1W_OFF  44032    // 57344: packed h words (h1 for L1/L2; h2 for head)
#define H2W_OFF  101376   // 57344: packed h2 words (L2 pass B)

__device__ __forceinline__ float sigmoidf_(float x) {
    return 1.0f / (1.0f + __expf(-x));
}
__device__ __forceinline__ float tanhf_(float x) {
    float ax = fabsf(x);
    float e  = __expf(-2.0f * ax);
    float t  = (1.0f - e) / (1.0f + e);
    return x >= 0.0f ? t : -t;
}

// Flags: agent-scope RMW + agent-scope poll (proven R2/R5). Back-pressure edges only.
__device__ __forceinline__ u32 flag_peek(const u32* p) {
    return __hip_atomic_load(p, __ATOMIC_RELAXED, __HIP_MEMORY_SCOPE_AGENT);
}
__device__ __forceinline__ void wait_ge(u32* p, u32 v) {
    while (__hip_atomic_load(p, __ATOMIC_RELAXED, __HIP_MEMORY_SCOPE_AGENT) < v)
        __builtin_amdgcn_s_sleep(1);
}
__device__ __forceinline__ void flag_add(u32* p) {
    __hip_atomic_fetch_add(p, 1u, __ATOMIC_RELAXED, __HIP_MEMORY_SCOPE_AGENT);
}
// Tagged-word publish: relaxed system-scope atomic store. Tag is IN the word ->
// no ordering vs anything else is needed; word is self-validating.
__device__ __forceinline__ void astore8w(u64* p, u64 v) {
    __hip_atomic_store(p, v, __ATOMIC_RELAXED, __HIP_MEMORY_SCOPE_SYSTEM);
}
__device__ __forceinline__ u64 aload8w(const u64* p) {
    return __hip_atomic_load(p, __ATOMIC_RELAXED, __HIP_MEMORY_SCOPE_SYSTEM);
}

// Poll-stage ONE 49KB tagged buffer (6144 words) into LDS raw-word layout.
// Each thread owns 12 lane-coalesced words; re-loads all 12 per round (branch-free
// load batch), commits those whose tag matches. soff[i] precomputed per thread.
// R11 lesson: do NOT widen rounds (24-load merged rounds ~2x round latency and
// start the live poll too early -> net loss). Keep 12-load rounds, serial polls.
__device__ __forceinline__ void stage_poll(char* smem, int ldsOff, const u64* g,
                                           u32 exp, int tid, const int* soff) {
    u32 pend = 0xFFFu;
    do {
        u64 vv[12];
        #pragma unroll
        for (int i = 0; i < 12; ++i)
            vv[i] = aload8w(g + i*512 + tid);
        #pragma unroll
        for (int i = 0; i < 12; ++i) {
            if ((pend & (1u << i)) && (u32)(vv[i] >> 48) == exp) {
                *(u64*)(smem + ldsOff + soff[i]) = vv[i];
                pend &= ~(1u << i);
            }
        }
        if (pend) __builtin_amdgcn_s_sleep(1);
    } while (pend);
}

// Build a half8 fragment (8 consecutive k-values) from 3 packed LDS words.
__device__ __forceinline__ half8 frag_pk(const char* p) {
    const u64* q = (const u64*)p;
    u64 w0 = q[0], w1 = q[1], w2 = q[2];
    u32 b = (u32)(w0 >> 32), c = (u32)w1, d = (u32)(w1 >> 32);
    union { u32 u[4]; half8 h; } U;
    U.u[0] = (u32)w0;
    U.u[1] = (b & 0xffffu) | (c << 16);
    U.u[2] = (c >> 16) | (d << 16);
    U.u[3] = (u32)w2;
    return U.h;
}
// LDS byte offset of word (jt, row, wi): ((jt*32+row)*7 + wi)*8
#define WB(jt,row,wi) (((jt)*224 + (row)*7 + (wi)) * 8)

// ---------------- prep kernels (weights -> fp16 fragment-linear) ----------------
__global__ void pack_w1(const float* __restrict__ Wih, const float* __restrict__ Whh,
                        f16* __restrict__ Wp) {
    int idx = blockIdx.x * 256 + threadIdx.x;
    if (idx >= 4*32*18*512) return;
    int j    = idx & 7;
    int lane = (idx >> 3) & 63;
    int kt   = (idx >> 9) % 18;
    int r    = (idx >> 9) / 18;
    int jt   = r & 31;
    int g    = r >> 5;
    int n = g*512 + jt*16 + (lane & 15);
    int k = kt*32 + (lane >> 4)*8 + j;
    float v = (k < 64) ? Wih[n*64 + k] : Whh[n*512 + (k - 64)];
    Wp[idx] = (f16)v;
}

__global__ void pack_w2(const float* __restrict__ Wih, const float* __restrict__ Whh,
                        f16* __restrict__ Wp) {
    int idx = blockIdx.x * 256 + threadIdx.x;
    if (idx >= 4*32*32*512) return;
    int j    = idx & 7;
    int lane = (idx >> 3) & 63;
    int kt   = (idx >> 9) & 31;
    int r    = idx >> 14;
    int jt   = r & 31;
    int g    = r >> 5;
    int n = g*512 + jt*16 + (lane & 15);
    int k = kt*32 + (lane >> 4)*8 + j;
    float v = (k < 512) ? Wih[n*512 + k] : Whh[n*512 + (k - 512)];
    Wp[idx] = (f16)v;
}

__global__ void pack_wo(const float* __restrict__ Wout, f16* __restrict__ Wp) {
    int idx = blockIdx.x * 256 + threadIdx.x;
    if (idx >= 4*16*512) return;
    int j    = idx & 7;
    int lane = (idx >> 3) & 63;
    int kt   = (idx >> 9) & 15;
    int nt   = idx >> 13;
    int n = nt*16 + (lane & 15);
    int k = kt*32 + (lane >> 4)*8 + j;
    Wp[idx] = (f16)Wout[n*512 + k];
}

__global__ void bias_sum(const float* __restrict__ a1, const float* __restrict__ b1,
                         const float* __restrict__ a2, const float* __restrict__ b2,
                         float* __restrict__ s1, float* __restrict__ s2) {
    int i = blockIdx.x * 256 + threadIdx.x;
    if (i >= 2048) return;
    s1[i] = a1[i] + b1[i];
    s2[i] = a2[i] + b2[i];
}

// ---------------- persistent self-timed kernel ----------------
// R13 = R12 resubmitted verbatim (R7 bench was an infra failure: "container
// failed twice", no kernel verdict). R12 = R9 base (best: 4754 us) + ONE
// conceptual change: move independent ops into the stage_poll's latency shadow.
//  (a) L1: x_{t+1} loaded into REGISTERS at iteration top (hidden under ~1.5us
//      of MFMA/pointwise), written to LDS in the tail with no vmcnt stall.
//  (b) L1/L2: tid0's back-pressure guard (a2 / aH, both stale-satisfied) is
//      PREFETCH-VERIFIED: flag load issued before the stage_poll, value checked
//      after it; spin only in the rare unsatisfied case. Guard semantics
//      unchanged (verify still precedes the next publish to the guarded slot).
// R11's stage_poll2 merge stays reverted (proven -1.2us/step).
__global__ __launch_bounds__(512, 1) void lstm_persist(
    const float* __restrict__ x,
    const f16*  __restrict__ W1p,
    const f16*  __restrict__ W2p,
    const f16*  __restrict__ Wop,
    const float* __restrict__ bs1,
    const float* __restrict__ bs2,
    const float* __restrict__ bout,
    u64*  __restrict__ h1w,     // [8][2][6144] tagged words
    u64*  __restrict__ h2w,     // [8][2][6144]
    float* __restrict__ y,
    u32*  __restrict__ arr2,    // [2][1024]
    u32*  __restrict__ arrH)    // [2][1024]
{
    __shared__ __align__(16) char smem[158720];
    float* RED = (float*)(smem + RED_OFF);
    float* CC  = (float*)(smem + CC_OFF);

    const int wg   = blockIdx.x;
    const int tid  = threadIdx.x;
    const int lane = tid & 63;
    const int w    = tid >> 6;
    const int col  = lane & 15;
    const int quad = lane >> 4;

    // staging LDS offsets for this thread's 12 words
    int soff[12];
    #pragma unroll
    for (int i = 0; i < 12; ++i) {
        const int ww = i*512 + tid;
        const int jt_ = ww / 192, rr = ww - jt_*192;
        soff[i] = WB(jt_, rr/6, rr%6);
    }
    // publisher params (valid for tid<192): word tid = r*6 + i of own slice
    const int pr  = tid / 6, pi = tid - pr*6;
    const int pj  = pi % 3;
    const int pc0 = pr*16 + (pi/3)*8 + pj*3;   // first col of this word
    const u16* hb = (const u16*)(smem + HB_OFF);

    if (wg < 64) {
        // ================= layer 1 =================
        const int jt = wg & 31, bhalf = wg >> 5;
        const int gp = w & 1, kq = w >> 1;
        half8 wrx[2];
        half8 wrh[2][4];
        if (kq < 2) {
            #pragma unroll
            for (int gi = 0; gi < 2; ++gi)
                wrx[gi] = *(const half8*)(W1p + ((size_t)(((gp*2+gi)*32 + jt)*18 + kq)*64 + lane)*8);
        }
        #pragma unroll
        for (int gi = 0; gi < 2; ++gi)
            #pragma unroll
            for (int k = 0; k < 4; ++k) {
                const int kt = 2 + kq*4 + k;
                wrh[gi][k] = *(const half8*)(W1p + ((size_t)(((gp*2+gi)*32 + jt)*18 + kt)*64 + lane)*8);
            }
        float bsr[4];
        #pragma unroll
        for (int g = 0; g < 4; ++g) bsr[g] = bs1[g*512 + jt*16 + (tid & 15)];
        CC[tid] = 0.f;

        u32* a2 = arr2 + bhalf*1024;
        const int lbx = tid >> 4, kcx = tid & 15;
        const float* xbase = x + (size_t)(bhalf*32 + lbx)*T_*(size_t)IN_ + ((kcx ^ (lbx & 7)) * 4);

        // prologue: x_0 + h1[-1] (slot 7, tag 0 = zeroed buffer)
        *(float4*)(smem + XS_OFF + tid*16) = *(const float4*)xbase;
        stage_poll(smem, H1W_OFF, h1w + (size_t)(7*2 + bhalf)*NWORD, 0u, tid, soff);
        __syncthreads();

        for (int t = 0; t < T_; ++t) {
            // (a) x_{t+1} -> registers at iteration top; MFMA+pointwise hide it
            float4 xreg;
            if (t + 1 < T_) xreg = *(const float4*)(xbase + (size_t)(t+1)*IN_);

            floatx4 acc[2][2] = {{{0.f,0.f,0.f,0.f},{0.f,0.f,0.f,0.f}},
                                 {{0.f,0.f,0.f,0.f},{0.f,0.f,0.f,0.f}}};
            #pragma unroll
            for (int m = 0; m < 2; ++m) {
                const int lb_a = m*16 + col, sw = lb_a & 7;
                if (kq < 2) {   // x-part: this kq's 32-col tile
                    const int fg = kq*8 + quad*2;
                    float4 u = *(const float4*)(smem + XS_OFF + ((size_t)lb_a*16 + (fg ^ sw))*16);
                    float4 v = *(const float4*)(smem + XS_OFF + ((size_t)lb_a*16 + ((fg+1) ^ sw))*16);
                    half8 a = (half8){(f16)u.x,(f16)u.y,(f16)u.z,(f16)u.w,
                                      (f16)v.x,(f16)v.y,(f16)v.z,(f16)v.w};
                    acc[0][m] = MFMA16(a, wrx[0], acc[0][m]);
                    acc[1][m] = MFMA16(a, wrx[1], acc[1][m]);
                }
                #pragma unroll
                for (int k = 0; k < 4; ++k) {
                    const int kc = kq*16 + k*4 + quad;
                    half8 a = frag_pk(smem + H1W_OFF + WB(kc>>1, lb_a, (kc&1)*3));
                    acc[0][m] = MFMA16(a, wrh[0][k], acc[0][m]);
                    acc[1][m] = MFMA16(a, wrh[1][k], acc[1][m]);
                }
            }
            #pragma unroll
            for (int gi = 0; gi < 2; ++gi) {
                const int g = gp*2 + gi;
                #pragma unroll
                for (int m = 0; m < 2; ++m)
                    #pragma unroll
                    for (int r = 0; r < 4; ++r)
                        RED[kq*2048 + g*512 + (m*16 + quad*4 + r)*16 + col] = acc[gi][m][r];
            }
            __syncthreads();
            {   // 4-way kq sum + pointwise -> HB
                float gt[4];
                #pragma unroll
                for (int g = 0; g < 4; ++g)
                    gt[g] = RED[       g*512 + tid] + RED[2048 + g*512 + tid]
                          + RED[4096 + g*512 + tid] + RED[6144 + g*512 + tid] + bsr[g];
                const float i_ = sigmoidf_(gt[0]);
                const float f_ = sigmoidf_(gt[1]);
                const float g_ = tanhf_(gt[2]);
                const float o_ = sigmoidf_(gt[3]);
                const float cn = f_ * CC[tid] + i_ * g_;
                CC[tid] = cn;
                ((f16*)(smem + HB_OFF))[tid] = (f16)(o_ * tanhf_(cn));
            }
            __syncthreads();
            // publish h1[t] (tagged words, one-way stores) -- earliest possible
            if (tid < 192) {
                u64 wv = (u64)hb[pc0] | ((u64)hb[pc0+1] << 16)
                       | ((pj < 2) ? ((u64)hb[pc0+2] << 32) : 0)
                       | ((u64)(u32)(t + 1) << 48);
                astore8w(h1w + (size_t)((t & 7)*2 + bhalf)*NWORD + jt*192 + tid, wv);
            }
            // (b) guard prefetch: issue flag load now, verify AFTER the poll
            const bool needA2 = (tid == 0) && (t + 1 < T_) && (t + 1 >= SLOTS);
            u32 fA2 = needA2 ? flag_peek(a2 + (t + 1 - SLOTS)) : 32u;
            if (t + 1 < T_) {
                // x_{t+1}: reg -> LDS, no global wait (load issued at iter top)
                *(float4*)(smem + XS_OFF + tid*16) = xreg;
                // stage h1[t] (just published by self + 31 peers): the poll IS the sync
                stage_poll(smem, H1W_OFF, h1w + (size_t)((t & 7)*2 + bhalf)*NWORD,
                           (u32)(t + 1), tid, soff);
            }
            if (needA2 && fA2 < 32u) wait_ge(a2 + (t + 1 - SLOTS), 32u);
            __syncthreads();   // staged data ready; store-acks drain hidden behind poll
        }
    } else if (wg < 128) {
        // ================= layer 2 =================
        const int v = wg - 64;
        const int jt = v & 31, bhalf = v >> 5;
        const int gp = w & 1, kq = w >> 1;
        half8 wrA[2][4], wrB[2][4];
        #pragma unroll
        for (int gi = 0; gi < 2; ++gi)
            #pragma unroll
            for (int k = 0; k < 4; ++k) {
                const int ktA = kq*4 + k;        // h1 half (K 0..511)
                const int ktB = 16 + kq*4 + k;   // h2 half (K 512..1023)
                wrA[gi][k] = *(const half8*)(W2p + ((size_t)(((gp*2+gi)*32 + jt)*32 + ktA)*64 + lane)*8);
                wrB[gi][k] = *(const half8*)(W2p + ((size_t)(((gp*2+gi)*32 + jt)*32 + ktB)*64 + lane)*8);
            }
        float bsr[4];
        #pragma unroll
        for (int g = 0; g < 4; ++g) bsr[g] = bs2[g*512 + jt*16 + (tid & 15)];
        CC[tid] = 0.f;

        u32* a2 = arr2 + bhalf*1024;
        u32* aH = arrH + bhalf*1024;

        // prologue: h1[0] (tag 1) then h2[-1] (slot 7, tag 0) -- serial polls (R9)
        stage_poll(smem, H1W_OFF, h1w + (size_t)(0*2 + bhalf)*NWORD, 1u, tid, soff);
        stage_poll(smem, H2W_OFF, h2w + (size_t)(7*2 + bhalf)*NWORD, 0u, tid, soff);
        __syncthreads();

        for (int t2 = 0; t2 < T_; ++t2) {
            floatx4 acc[2][2] = {{{0.f,0.f,0.f,0.f},{0.f,0.f,0.f,0.f}},
                                 {{0.f,0.f,0.f,0.f},{0.f,0.f,0.f,0.f}}};
            #pragma unroll
            for (int m = 0; m < 2; ++m) {   // pass A (h1[t2])
                const int lb_a = m*16 + col;
                #pragma unroll
                for (int k = 0; k < 4; ++k) {
                    const int kc = kq*16 + k*4 + quad;
                    half8 a = frag_pk(smem + H1W_OFF + WB(kc>>1, lb_a, (kc&1)*3));
                    acc[0][m] = MFMA16(a, wrA[0][k], acc[0][m]);
                    acc[1][m] = MFMA16(a, wrA[1][k], acc[1][m]);
                }
            }
            #pragma unroll
            for (int m = 0; m < 2; ++m) {   // pass B (h2[t2-1])
                const int lb_a = m*16 + col;
                #pragma unroll
                for (int k = 0; k < 4; ++k) {
                    const int kc = kq*16 + k*4 + quad;
                    half8 a = frag_pk(smem + H2W_OFF + WB(kc>>1, lb_a, (kc&1)*3));
                    acc[0][m] = MFMA16(a, wrB[0][k], acc[0][m]);
                    acc[1][m] = MFMA16(a, wrB[1][k], acc[1][m]);
                }
            }
            #pragma unroll
            for (int gi = 0; gi < 2; ++gi) {
                const int g = gp*2 + gi;
                #pragma unroll
                for (int m = 0; m < 2; ++m)
                    #pragma unroll
                    for (int r = 0; r < 4; ++r)
                        RED[kq*2048 + g*512 + (m*16 + quad*4 + r)*16 + col] = acc[gi][m][r];
            }
            __syncthreads();
            {   // 4-way kq sum + pointwise -> HB
                float gt[4];
                #pragma unroll
                for (int g = 0; g < 4; ++g)
                    gt[g] = RED[       g*512 + tid] + RED[2048 + g*512 + tid]
                          + RED[4096 + g*512 + tid] + RED[6144 + g*512 + tid] + bsr[g];
                const float i_ = sigmoidf_(gt[0]);
                const float f_ = sigmoidf_(gt[1]);
                const float g_ = tanhf_(gt[2]);
                const float o_ = sigmoidf_(gt[3]);
                const float cn = f_ * CC[tid] + i_ * g_;
                CC[tid] = cn;
                ((f16*)(smem + HB_OFF))[tid] = (f16)(o_ * tanhf_(cn));
            }
            __syncthreads();
            // publish h2[t2] -- earliest possible, one-way stores
            if (tid < 192) {
                u64 wv = (u64)hb[pc0] | ((u64)hb[pc0+1] << 16)
                       | ((pj < 2) ? ((u64)hb[pc0+2] << 32) : 0)
                       | ((u64)(u32)(t2 + 1) << 48);
                astore8w(h2w + (size_t)((t2 & 7)*2 + bhalf)*NWORD + jt*192 + tid, wv);
            }
            // done reading h1[t2] & h2[t2-1]: release L1's slot guard
            if (tid == 0) flag_add(a2 + t2);
            // (b) guard prefetch: issue aH load now, verify AFTER the polls
            const bool needAH = (tid == 0) && (t2 + 1 < T_) && (t2 + 1 >= SLOTS);
            u32 fAH = needAH ? flag_peek(aH + (t2 + 1 - SLOTS)) : 1u;
            if (t2 + 1 < T_) {
                // serial polls, R9 order: h1[t2+1] (satisfied; acts as delay)
                // then h2[t2] (live edge; succeeds round 1 by then)
                stage_poll(smem, H1W_OFF, h1w + (size_t)(((t2+1) & 7)*2 + bhalf)*NWORD,
                           (u32)(t2 + 2), tid, soff);
                stage_poll(smem, H2W_OFF, h2w + (size_t)((t2 & 7)*2 + bhalf)*NWORD,
                           (u32)(t2 + 1), tid, soff);
            }
            if (needAH && fAH < 1u) wait_ge(aH + (t2 + 1 - SLOTS), 1u);
            __syncthreads();
        }
    } else {
        // ================= head =================
        const int bhalf = wg - 128;
        const int nt = w & 3, kh = w >> 2;
        half8 wr[8];
        #pragma unroll
        for (int k = 0; k < 8; ++k) {
            const int kt = kh*8 + k;
            wr[k] = *(const half8*)(Wop + ((size_t)(nt*16 + kt)*64 + lane)*8);
        }
        const float boutr = bout[nt*16 + col];
        u32* aH = arrH + bhalf*1024;
        const int lb0 = col, lb1 = 16 + col;

        // prologue: stage h2[0]
        stage_poll(smem, H1W_OFF, h2w + (size_t)(0*2 + bhalf)*NWORD, 1u, tid, soff);
        __syncthreads();
        if (tid == 0) flag_add(aH + 0);

        for (int t3 = 0; t3 < T_; ++t3) {
            floatx4 acc0 = {0.f,0.f,0.f,0.f}, acc1 = {0.f,0.f,0.f,0.f};
            #pragma unroll
            for (int k = 0; k < 8; ++k) {
                const int kc = (kh*8 + k)*4 + quad;
                half8 a0  = frag_pk(smem + H1W_OFF + WB(kc>>1, lb0, (kc&1)*3));
                half8 a1v = frag_pk(smem + H1W_OFF + WB(kc>>1, lb1, (kc&1)*3));
                acc0 = MFMA16(a0,  wr[k], acc0);
                acc1 = MFMA16(a1v, wr[k], acc1);
            }
            if (kh == 1) {
                #pragma unroll
                for (int r = 0; r < 4; ++r) {
                    RED[(nt*2+0)*256 + (quad*4 + r)*16 + col] = acc0[r];
                    RED[(nt*2+1)*256 + (quad*4 + r)*16 + col] = acc1[r];
                }
            }
            __syncthreads();
            if (kh == 0) {
                #pragma unroll
                for (int r = 0; r < 4; ++r) {
                    const float v0 = acc0[r] + RED[(nt*2+0)*256 + (quad*4 + r)*16 + col] + boutr;
                    const float v1 = acc1[r] + RED[(nt*2+1)*256 + (quad*4 + r)*16 + col] + boutr;
                    const int b0 = bhalf*32 +  0 + quad*4 + r;
                    const int b1 = bhalf*32 + 16 + quad*4 + r;
                    y[((size_t)b0*T_ + t3)*OUT_ + nt*16 + col] = v0;
                    y[((size_t)b1*T_ + t3)*OUT_ + nt*16 + col] = v1;
                }
            }
            __syncthreads();   // RED reuse
            if (t3 + 1 < T_) {
                stage_poll(smem, H1W_OFF, h2w + (size_t)(((t3+1) & 7)*2 + bhalf)*NWORD,
                           (u32)(t3 + 2), tid, soff);
                __syncthreads();               // staging complete
                if (tid == 0) flag_add(aH + (t3 + 1));   // release L2's slot guard
            }
        }
    }
}

// ---------------- launch ----------------
extern "C" void kernel_launch(void* const* d_in, const int* in_sizes, int n_in,
                              void* d_out, int out_size, void* d_ws, size_t ws_size,
                              hipStream_t stream) {
    const float* x    = (const float*)d_in[0];
    const float* Wih1 = (const float*)d_in[1];
    const float* Whh1 = (const float*)d_in[2];
    const float* bih1 = (const float*)d_in[3];
    const float* bhh1 = (const float*)d_in[4];
    const float* Wih2 = (const float*)d_in[5];
    const float* Whh2 = (const float*)d_in[6];
    const float* bih2 = (const float*)d_in[7];
    const float* bhh2 = (const float*)d_in[8];
    const float* Wout = (const float*)d_in[9];
    const float* bout = (const float*)d_in[10];
    float* y = (float*)d_out;

    char* ws = (char*)d_ws;
    f16*   W1p   = (f16*)(ws + 0);           // 2,359,296 B
    f16*   W2p   = (f16*)(ws + 2359296);     // 4,194,304 B
    f16*   Wop   = (f16*)(ws + 6553600);     //    65,536 B
    float* bs1   = (float*)(ws + 6619136);   //     8,192 B
    float* bs2   = (float*)(ws + 6627328);   //     8,192 B
    u64*   h1w   = (u64*)(ws + 6635520);     //   786,432 B (8 slots x 2 bh x 6144 words)
    u64*   h2w   = (u64*)(ws + 7421952);     //   786,432 B
    u32*   arr2  = (u32*)(ws + 8208384);     //     8,192 B
    u32*   arrH  = (u32*)(ws + 8216576);     //     8,192 B

    // zero tagged-word buffers (tag 0 = step -1 state) + back-pressure counters
    hipMemsetAsync(ws + 6635520, 0, 1589248, stream);

    pack_w1<<<4608, 256, 0, stream>>>(Wih1, Whh1, W1p);
    pack_w2<<<8192, 256, 0, stream>>>(Wih2, Whh2, W2p);
    pack_wo<<<128, 256, 0, stream>>>(Wout, Wop);
    bias_sum<<<8, 256, 0, stream>>>(bih1, bhh1, bih2, bhh2, bs1, bs2);

    lstm_persist<<<NWG, 512, 0, stream>>>(x, W1p, W2p, Wop, bs1, bs2, bout,
                                          h1w, h2w, y, arr2, arrH);
}

// Round 9
// 4372.770 us; speedup vs baseline: 1.6253x; 1.0945x over previous
//
#include <hip/hip_runtime.h>

#define B_    64
#define T_    1024
#define IN_   64
#define H_    512
#define OUT_  64
#define SLOTS 8
#define NWG   256
#define NROLE 130
#define NWORD 6144      // words per (bhalf, slot): 32 jt * 32 rows * 6 words
#define RSLOT (8*NWORD) // words per ring (8 slots)

typedef _Float16 f16;
typedef _Float16 half8 __attribute__((ext_vector_type(8)));
typedef float    floatx4 __attribute__((ext_vector_type(4)));
typedef unsigned int u32;
typedef unsigned short u16;
typedef unsigned long long u64;

#define MFMA16(a,b,c) __builtin_amdgcn_mfma_f32_16x16x32_f16((a),(b),(c),0,0,0)

// LDS layout (158720 B, 1 WG/CU)
#define XS_OFF   0        // 8KB: L1 x-stage (L2 reuses first 4B as esc flag)
#define HB_OFF   8192     // 1KB: pointwise h output (f16[512])
#define CC_OFF   9216     // 2KB: c-state
#define RED_OFF  11264    // 32KB: 4 kq-regions x 8KB partial-sum
#define H1W_OFF  44032    // 57344: packed h words (h1 for L1/L2; h2 for head)
#define H2W_OFF  101376   // 57344: packed h2 words (L2 pass B; L1 reuses first 4B as esc)

__device__ __forceinline__ float sigmoidf_(float x) {
    return 1.0f / (1.0f + __expf(-x));
}
__device__ __forceinline__ float tanhf_(float x) {
    float ax = fabsf(x);
    float e  = __expf(-2.0f * ax);
    float t  = (1.0f - e) / (1.0f + e);
    return x >= 0.0f ? t : -t;
}

// Flags: agent-scope RMW + agent-scope poll (proven R2/R5). Back-pressure edges only.
__device__ __forceinline__ u32 flag_peek(const u32* p) {
    return __hip_atomic_load(p, __ATOMIC_RELAXED, __HIP_MEMORY_SCOPE_AGENT);
}
__device__ __forceinline__ void wait_ge(u32* p, u32 v) {
    while (__hip_atomic_load(p, __ATOMIC_RELAXED, __HIP_MEMORY_SCOPE_AGENT) < v)
        __builtin_amdgcn_s_sleep(1);
}
__device__ __forceinline__ void flag_add(u32* p) {
    __hip_atomic_fetch_add(p, 1u, __ATOMIC_RELAXED, __HIP_MEMORY_SCOPE_AGENT);
}
// System-scope tagged-word ops (MALL coherence point) -- cross-XCD edges. Proven R9.
__device__ __forceinline__ void astore8w(u64* p, u64 v) {
    __hip_atomic_store(p, v, __ATOMIC_RELAXED, __HIP_MEMORY_SCOPE_SYSTEM);
}
__device__ __forceinline__ u64 aload8w(const u64* p) {
    return __hip_atomic_load(p, __ATOMIC_RELAXED, __HIP_MEMORY_SCOPE_SYSTEM);
}
// Agent-scope tagged-word ops -- intra-XCD ring edges (shared XCD L2 is the
// physical coherence point when all ring members sit on one XCD).
__device__ __forceinline__ void astore8a(u64* p, u64 v) {
    __hip_atomic_store(p, v, __ATOMIC_RELAXED, __HIP_MEMORY_SCOPE_AGENT);
}
__device__ __forceinline__ u64 aload8a(const u64* p) {
    return __hip_atomic_load(p, __ATOMIC_RELAXED, __HIP_MEMORY_SCOPE_AGENT);
}

// Poll-stage ONE 49KB tagged buffer (6144 words) into LDS. 12-load rounds (R11
// lesson: never widen rounds).
__device__ __forceinline__ void stage_poll(char* smem, int ldsOff, const u64* g,
                                           u32 exp, int tid, const int* soff) {
    u32 pend = 0xFFFu;
    do {
        u64 vv[12];
        #pragma unroll
        for (int i = 0; i < 12; ++i)
            vv[i] = aload8w(g + i*512 + tid);
        #pragma unroll
        for (int i = 0; i < 12; ++i) {
            if ((pend & (1u << i)) && (u32)(vv[i] >> 48) == exp) {
                *(u64*)(smem + ldsOff + soff[i]) = vv[i];
                pend &= ~(1u << i);
            }
        }
        if (pend) __builtin_amdgcn_s_sleep(1);
    } while (pend);
}

// Ring poll: agent-scope loads from the ring copy (gr) when the ring is
// XCD-coherent; system loads from the always-published system copy (gs) when
// not, or after a sticky escape (safety: completes even if agent semantics
// differ from the hypothesis -- at R9 speed, never wrong, never hung).
__device__ __forceinline__ void stage_poll_r(char* smem, int ldsOff,
                                             const u64* gr, const u64* gs,
                                             u32 exp, int tid, const int* soff,
                                             int coh, int* esc) {
    u32 pend = 0xFFFu;
    int rounds = 0;
    bool useSys = (!coh) || (*esc != 0);
    do {
        u64 vv[12];
        if (!useSys) {
            #pragma unroll
            for (int i = 0; i < 12; ++i) vv[i] = aload8a(gr + i*512 + tid);
        } else {
            #pragma unroll
            for (int i = 0; i < 12; ++i) vv[i] = aload8w(gs + i*512 + tid);
        }
        #pragma unroll
        for (int i = 0; i < 12; ++i) {
            if ((pend & (1u << i)) && (u32)(vv[i] >> 48) == exp) {
                *(u64*)(smem + ldsOff + soff[i]) = vv[i];
                pend &= ~(1u << i);
            }
        }
        if (pend) {
            __builtin_amdgcn_s_sleep(1);
            if (!useSys && ++rounds >= 1024) { useSys = true; *esc = 1; }
        }
    } while (pend);
}

// Build a half8 fragment (8 consecutive k-values) from 3 packed LDS words.
__device__ __forceinline__ half8 frag_pk(const char* p) {
    const u64* q = (const u64*)p;
    u64 w0 = q[0], w1 = q[1], w2 = q[2];
    u32 b = (u32)(w0 >> 32), c = (u32)w1, d = (u32)(w1 >> 32);
    union { u32 u[4]; half8 h; } U;
    U.u[0] = (u32)w0;
    U.u[1] = (b & 0xffffu) | (c << 16);
    U.u[2] = (c >> 16) | (d << 16);
    U.u[3] = (u32)w2;
    return U.h;
}
// LDS byte offset of word (jt, row, wi): ((jt*32+row)*7 + wi)*8
#define WB(jt,row,wi) (((jt)*224 + (row)*7 + (wi)) * 8)

// ---------------- prep kernels (weights -> fp16 fragment-linear) ----------------
__global__ void pack_w1(const float* __restrict__ Wih, const float* __restrict__ Whh,
                        f16* __restrict__ Wp) {
    int idx = blockIdx.x * 256 + threadIdx.x;
    if (idx >= 4*32*18*512) return;
    int j    = idx & 7;
    int lane = (idx >> 3) & 63;
    int kt   = (idx >> 9) % 18;
    int r    = (idx >> 9) / 18;
    int jt   = r & 31;
    int g    = r >> 5;
    int n = g*512 + jt*16 + (lane & 15);
    int k = kt*32 + (lane >> 4)*8 + j;
    float v = (k < 64) ? Wih[n*64 + k] : Whh[n*512 + (k - 64)];
    Wp[idx] = (f16)v;
}

__global__ void pack_w2(const float* __restrict__ Wih, const float* __restrict__ Whh,
                        f16* __restrict__ Wp) {
    int idx = blockIdx.x * 256 + threadIdx.x;
    if (idx >= 4*32*32*512) return;
    int j    = idx & 7;
    int lane = (idx >> 3) & 63;
    int kt   = (idx >> 9) & 31;
    int r    = idx >> 14;
    int jt   = r & 31;
    int g    = r >> 5;
    int n = g*512 + jt*16 + (lane & 15);
    int k = kt*32 + (lane >> 4)*8 + j;
    float v = (k < 512) ? Wih[n*512 + k] : Whh[n*512 + (k - 512)];
    Wp[idx] = (f16)v;
}

__global__ void pack_wo(const float* __restrict__ Wout, f16* __restrict__ Wp) {
    int idx = blockIdx.x * 256 + threadIdx.x;
    if (idx >= 4*16*512) return;
    int j    = idx & 7;
    int lane = (idx >> 3) & 63;
    int kt   = (idx >> 9) & 15;
    int nt   = idx >> 13;
    int n = nt*16 + (lane & 15);
    int k = kt*32 + (lane >> 4)*8 + j;
    Wp[idx] = (f16)Wout[n*512 + k];
}

__global__ void bias_sum(const float* __restrict__ a1, const float* __restrict__ b1,
                         const float* __restrict__ a2, const float* __restrict__ b2,
                         float* __restrict__ s1, float* __restrict__ s2) {
    int i = blockIdx.x * 256 + threadIdx.x;
    if (i >= 2048) return;
    s1[i] = a1[i] + b1[i];
    s2[i] = a2[i] + b2[i];
}

// ---------------- persistent self-timed kernel ----------------
// R14 = R13 dataflow + XCD-local recurrence rings.
// Roles (claimed at runtime via XCC_ID + per-XCD rank + CAS):
//   0..31  L1 bhalf0 (ring 0, pref XCD 0)   32..63  L1 bhalf1 (ring 1, XCD 1)
//   64..95 L2 bhalf0 (ring 2, pref XCD 2)   96..127 L2 bhalf1 (ring 3, XCD 3)
//   128..129 head (pref XCD 4)              extras exit.
// Each ring checks all 32 members share an XCD; if so its recurrence
// (h1 for L1 rings, h2 for L2 rings) uses agent-scope ops on a ring-private
// buffer -- coherent through the SHARED XCD L2 (fast hop). System-scope copies
// (h1w for L2's pass A, h2w for head) are ALWAYS published, so non-coherent
// rings and the sticky escape hatch fall back to the proven R9 path.
__global__ __launch_bounds__(512, 1) void lstm_persist(
    const float* __restrict__ x,
    const f16*  __restrict__ W1p,
    const f16*  __restrict__ W2p,
    const f16*  __restrict__ Wop,
    const float* __restrict__ bs1,
    const float* __restrict__ bs2,
    const float* __restrict__ bout,
    u64*  __restrict__ h1w,     // [8][2][6144] tagged words (system copy)
    u64*  __restrict__ h2w,     // [8][2][6144] (system copy)
    u64*  __restrict__ hring,   // [4 rings][8][6144] ring-local copies
    float* __restrict__ y,
    u32*  __restrict__ arr2,    // [2][1024]
    u32*  __restrict__ arrH,    // [2][1024]
    u32*  __restrict__ ctrl)    // claim/ring-init control block
{
    __shared__ __align__(16) char smem[158720];
    __shared__ int s_role, s_coh;
    float* RED = (float*)(smem + RED_OFF);
    float* CC  = (float*)(smem + CC_OFF);

    const int tid  = threadIdx.x;
    const int lane = tid & 63;
    const int w    = tid >> 6;
    const int col  = lane & 15;
    const int quad = lane >> 4;

    // ---- role claim (tid 0) ----
    u32 xcd;
    asm volatile("s_getreg_b32 %0, hwreg(HW_REG_XCC_ID)" : "=s"(xcd));
    xcd &= 7u;
    if (tid == 0) {
        u32* cnt     = ctrl;          // [8]
        u32* claimed = ctrl + 8;      // [1]
        u32* taken   = ctrl + 16;     // [130]
        u32* mx      = ctrl + 160;    // [128] member xcd+1
        u32* rcnt    = ctrl + 288;    // [4]
        int role = -1;
        u32 rank = __hip_atomic_fetch_add(&cnt[xcd], 1u, __ATOMIC_RELAXED, __HIP_MEMORY_SCOPE_AGENT);
        int pref = -1;
        if (xcd < 4u)       { if (rank < 32u) pref = (int)(xcd*32u + rank); }
        else if (xcd == 4u) { if (rank < 2u)  pref = 128 + (int)rank; }
        if (pref >= 0) {
            u32 e0 = 0;
            if (__hip_atomic_compare_exchange_strong(&taken[pref], &e0, 1u,
                    __ATOMIC_RELAXED, __ATOMIC_RELAXED, __HIP_MEMORY_SCOPE_AGENT))
                role = pref;
        }
        if (role < 0) {
            if (pref < 0)   // courtesy delay so preferred owners claim first
                for (int s = 0; s < 100; ++s) __builtin_amdgcn_s_sleep(64);
            while (role < 0) {
                if (__hip_atomic_load(claimed, __ATOMIC_RELAXED, __HIP_MEMORY_SCOPE_AGENT) >= (u32)NROLE)
                    break;
                for (int r = 0; r < NROLE; ++r) {
                    u32 e0 = 0;
                    if (__hip_atomic_load(&taken[r], __ATOMIC_RELAXED, __HIP_MEMORY_SCOPE_AGENT) == 0u &&
                        __hip_atomic_compare_exchange_strong(&taken[r], &e0, 1u,
                            __ATOMIC_RELAXED, __ATOMIC_RELAXED, __HIP_MEMORY_SCOPE_AGENT)) {
                        role = r; break;
                    }
                }
            }
        }
        int coh = 0;
        if (role >= 0) {
            __hip_atomic_fetch_add(claimed, 1u, __ATOMIC_RELAXED, __HIP_MEMORY_SCOPE_AGENT);
            if (role < 128) {   // ring member: exchange XCDs, check coherence
                const int ring = role >> 5;
                __hip_atomic_store(&mx[role], xcd + 1u, __ATOMIC_RELAXED, __HIP_MEMORY_SCOPE_AGENT);
                __hip_atomic_fetch_add(&rcnt[ring], 1u, __ATOMIC_RELEASE, __HIP_MEMORY_SCOPE_AGENT);
                while (__hip_atomic_load(&rcnt[ring], __ATOMIC_ACQUIRE, __HIP_MEMORY_SCOPE_AGENT) < 32u)
                    __builtin_amdgcn_s_sleep(1);
                coh = 1;
                u32 x0 = __hip_atomic_load(&mx[ring*32], __ATOMIC_RELAXED, __HIP_MEMORY_SCOPE_AGENT);
                for (int i = 1; i < 32; ++i)
                    if (__hip_atomic_load(&mx[ring*32 + i], __ATOMIC_RELAXED, __HIP_MEMORY_SCOPE_AGENT) != x0)
                        coh = 0;
            }
        }
        s_role = role;
        s_coh  = coh;
    }
    __syncthreads();
    const int role = s_role;
    const int coh  = s_coh;
    if (role < 0) return;

    // staging LDS offsets for this thread's 12 words
    int soff[12];
    #pragma unroll
    for (int i = 0; i < 12; ++i) {
        const int ww = i*512 + tid;
        const int jt_ = ww / 192, rr = ww - jt_*192;
        soff[i] = WB(jt_, rr/6, rr%6);
    }
    // publisher params (valid for tid<192): word tid = r*6 + i of own slice
    const int pr  = tid / 6, pi = tid - pr*6;
    const int pj  = pi % 3;
    const int pc0 = pr*16 + (pi/3)*8 + pj*3;
    const u16* hb = (const u16*)(smem + HB_OFF);

    if (role < 64) {
        // ================= layer 1 =================
        const int bhalf = role >> 5, jt = role & 31;
        u64* rbuf = hring + (size_t)bhalf * RSLOT;      // ring 0/1
        int* esc  = (int*)(smem + H2W_OFF);             // L1 never uses H2W
        if (tid == 0) *esc = 0;
        const int gp = w & 1, kq = w >> 1;
        half8 wrx[2];
        half8 wrh[2][4];
        if (kq < 2) {
            #pragma unroll
            for (int gi = 0; gi < 2; ++gi)
                wrx[gi] = *(const half8*)(W1p + ((size_t)(((gp*2+gi)*32 + jt)*18 + kq)*64 + lane)*8);
        }
        #pragma unroll
        for (int gi = 0; gi < 2; ++gi)
            #pragma unroll
            for (int k = 0; k < 4; ++k) {
                const int kt = 2 + kq*4 + k;
                wrh[gi][k] = *(const half8*)(W1p + ((size_t)(((gp*2+gi)*32 + jt)*18 + kt)*64 + lane)*8);
            }
        float bsr[4];
        #pragma unroll
        for (int g = 0; g < 4; ++g) bsr[g] = bs1[g*512 + jt*16 + (tid & 15)];
        CC[tid] = 0.f;

        u32* a2 = arr2 + bhalf*1024;
        const int lbx = tid >> 4, kcx = tid & 15;
        const float* xbase = x + (size_t)(bhalf*32 + lbx)*T_*(size_t)IN_ + ((kcx ^ (lbx & 7)) * 4);

        // prologue: x_0 + h1[-1] (slot 7, tag 0 = zeroed buffers)
        *(float4*)(smem + XS_OFF + tid*16) = *(const float4*)xbase;
        __syncthreads();   // esc visible
        stage_poll_r(smem, H1W_OFF, rbuf + (size_t)7*NWORD,
                     h1w + (size_t)(7*2 + bhalf)*NWORD, 0u, tid, soff, coh, esc);
        __syncthreads();

        for (int t = 0; t < T_; ++t) {
            float4 xreg;
            if (t + 1 < T_) xreg = *(const float4*)(xbase + (size_t)(t+1)*IN_);

            floatx4 acc[2][2] = {{{0.f,0.f,0.f,0.f},{0.f,0.f,0.f,0.f}},
                                 {{0.f,0.f,0.f,0.f},{0.f,0.f,0.f,0.f}}};
            #pragma unroll
            for (int m = 0; m < 2; ++m) {
                const int lb_a = m*16 + col, sw = lb_a & 7;
                if (kq < 2) {
                    const int fg = kq*8 + quad*2;
                    float4 u = *(const float4*)(smem + XS_OFF + ((size_t)lb_a*16 + (fg ^ sw))*16);
                    float4 v = *(const float4*)(smem + XS_OFF + ((size_t)lb_a*16 + ((fg+1) ^ sw))*16);
                    half8 a = (half8){(f16)u.x,(f16)u.y,(f16)u.z,(f16)u.w,
                                      (f16)v.x,(f16)v.y,(f16)v.z,(f16)v.w};
                    acc[0][m] = MFMA16(a, wrx[0], acc[0][m]);
                    acc[1][m] = MFMA16(a, wrx[1], acc[1][m]);
                }
                #pragma unroll
                for (int k = 0; k < 4; ++k) {
                    const int kc = kq*16 + k*4 + quad;
                    half8 a = frag_pk(smem + H1W_OFF + WB(kc>>1, lb_a, (kc&1)*3));
                    acc[0][m] = MFMA16(a, wrh[0][k], acc[0][m]);
                    acc[1][m] = MFMA16(a, wrh[1][k], acc[1][m]);
                }
            }
            #pragma unroll
            for (int gi = 0; gi < 2; ++gi) {
                const int g = gp*2 + gi;
                #pragma unroll
                for (int m = 0; m < 2; ++m)
                    #pragma unroll
                    for (int r = 0; r < 4; ++r)
                        RED[kq*2048 + g*512 + (m*16 + quad*4 + r)*16 + col] = acc[gi][m][r];
            }
            __syncthreads();
            {   // 4-way kq sum + pointwise -> HB
                float gt[4];
                #pragma unroll
                for (int g = 0; g < 4; ++g)
                    gt[g] = RED[       g*512 + tid] + RED[2048 + g*512 + tid]
                          + RED[4096 + g*512 + tid] + RED[6144 + g*512 + tid] + bsr[g];
                const float i_ = sigmoidf_(gt[0]);
                const float f_ = sigmoidf_(gt[1]);
                const float g_ = tanhf_(gt[2]);
                const float o_ = sigmoidf_(gt[3]);
                const float cn = f_ * CC[tid] + i_ * g_;
                CC[tid] = cn;
                ((f16*)(smem + HB_OFF))[tid] = (f16)(o_ * tanhf_(cn));
            }
            __syncthreads();
            // publish h1[t]: system copy always (L2 consumes); ring copy if coherent
            if (tid < 192) {
                u64 wv = (u64)hb[pc0] | ((u64)hb[pc0+1] << 16)
                       | ((pj < 2) ? ((u64)hb[pc0+2] << 32) : 0)
                       | ((u64)(u32)(t + 1) << 48);
                astore8w(h1w + (size_t)((t & 7)*2 + bhalf)*NWORD + jt*192 + tid, wv);
                if (coh) astore8a(rbuf + (size_t)(t & 7)*NWORD + jt*192 + tid, wv);
            }
            const bool needA2 = (tid == 0) && (t + 1 < T_) && (t + 1 >= SLOTS);
            u32 fA2 = needA2 ? flag_peek(a2 + (t + 1 - SLOTS)) : 32u;
            if (t + 1 < T_) {
                *(float4*)(smem + XS_OFF + tid*16) = xreg;
                stage_poll_r(smem, H1W_OFF, rbuf + (size_t)(t & 7)*NWORD,
                             h1w + (size_t)((t & 7)*2 + bhalf)*NWORD,
                             (u32)(t + 1), tid, soff, coh, esc);
            }
            if (needA2 && fA2 < 32u) wait_ge(a2 + (t + 1 - SLOTS), 32u);
            __syncthreads();
        }
    } else if (role < 128) {
        // ================= layer 2 =================
        const int v = role - 64;
        const int bhalf = v >> 5, jt = v & 31;
        u64* rbuf = hring + (size_t)(2 + bhalf) * RSLOT;   // ring 2/3
        int* esc  = (int*)(smem + XS_OFF);                 // L2 never uses XS
        if (tid == 0) *esc = 0;
        const int gp = w & 1, kq = w >> 1;
        half8 wrA[2][4], wrB[2][4];
        #pragma unroll
        for (int gi = 0; gi < 2; ++gi)
            #pragma unroll
            for (int k = 0; k < 4; ++k) {
                const int ktA = kq*4 + k;
                const int ktB = 16 + kq*4 + k;
                wrA[gi][k] = *(const half8*)(W2p + ((size_t)(((gp*2+gi)*32 + jt)*32 + ktA)*64 + lane)*8);
                wrB[gi][k] = *(const half8*)(W2p + ((size_t)(((gp*2+gi)*32 + jt)*32 + ktB)*64 + lane)*8);
            }
        float bsr[4];
        #pragma unroll
        for (int g = 0; g < 4; ++g) bsr[g] = bs2[g*512 + jt*16 + (tid & 15)];
        CC[tid] = 0.f;

        u32* a2 = arr2 + bhalf*1024;
        u32* aH = arrH + bhalf*1024;

        // prologue: h1[0] (system, tag 1) then h2[-1] (ring/system, slot 7 tag 0)
        __syncthreads();   // esc visible
        stage_poll(smem, H1W_OFF, h1w + (size_t)(0*2 + bhalf)*NWORD, 1u, tid, soff);
        stage_poll_r(smem, H2W_OFF, rbuf + (size_t)7*NWORD,
                     h2w + (size_t)(7*2 + bhalf)*NWORD, 0u, tid, soff, coh, esc);
        __syncthreads();

        for (int t2 = 0; t2 < T_; ++t2) {
            floatx4 acc[2][2] = {{{0.f,0.f,0.f,0.f},{0.f,0.f,0.f,0.f}},
                                 {{0.f,0.f,0.f,0.f},{0.f,0.f,0.f,0.f}}};
            #pragma unroll
            for (int m = 0; m < 2; ++m) {   // pass A (h1[t2])
                const int lb_a = m*16 + col;
                #pragma unroll
                for (int k = 0; k < 4; ++k) {
                    const int kc = kq*16 + k*4 + quad;
                    half8 a = frag_pk(smem + H1W_OFF + WB(kc>>1, lb_a, (kc&1)*3));
                    acc[0][m] = MFMA16(a, wrA[0][k], acc[0][m]);
                    acc[1][m] = MFMA16(a, wrA[1][k], acc[1][m]);
                }
            }
            #pragma unroll
            for (int m = 0; m < 2; ++m) {   // pass B (h2[t2-1])
                const int lb_a = m*16 + col;
                #pragma unroll
                for (int k = 0; k < 4; ++k) {
                    const int kc = kq*16 + k*4 + quad;
                    half8 a = frag_pk(smem + H2W_OFF + WB(kc>>1, lb_a, (kc&1)*3));
                    acc[0][m] = MFMA16(a, wrB[0][k], acc[0][m]);
                    acc[1][m] = MFMA16(a, wrB[1][k], acc[1][m]);
                }
            }
            #pragma unroll
            for (int gi = 0; gi < 2; ++gi) {
                const int g = gp*2 + gi;
                #pragma unroll
                for (int m = 0; m < 2; ++m)
                    #pragma unroll
                    for (int r = 0; r < 4; ++r)
                        RED[kq*2048 + g*512 + (m*16 + quad*4 + r)*16 + col] = acc[gi][m][r];
            }
            __syncthreads();
            {   // 4-way kq sum + pointwise -> HB
                float gt[4];
                #pragma unroll
                for (int g = 0; g < 4; ++g)
                    gt[g] = RED[       g*512 + tid] + RED[2048 + g*512 + tid]
                          + RED[4096 + g*512 + tid] + RED[6144 + g*512 + tid] + bsr[g];
                const float i_ = sigmoidf_(gt[0]);
                const float f_ = sigmoidf_(gt[1]);
                const float g_ = tanhf_(gt[2]);
                const float o_ = sigmoidf_(gt[3]);
                const float cn = f_ * CC[tid] + i_ * g_;
                CC[tid] = cn;
                ((f16*)(smem + HB_OFF))[tid] = (f16)(o_ * tanhf_(cn));
            }
            __syncthreads();
            // publish h2[t2]: system copy always (head consumes); ring copy if coherent
            if (tid < 192) {
                u64 wv = (u64)hb[pc0] | ((u64)hb[pc0+1] << 16)
                       | ((pj < 2) ? ((u64)hb[pc0+2] << 32) : 0)
                       | ((u64)(u32)(t2 + 1) << 48);
                astore8w(h2w + (size_t)((t2 & 7)*2 + bhalf)*NWORD + jt*192 + tid, wv);
                if (coh) astore8a(rbuf + (size_t)(t2 & 7)*NWORD + jt*192 + tid, wv);
            }
            if (tid == 0) flag_add(a2 + t2);
            const bool needAH = (tid == 0) && (t2 + 1 < T_) && (t2 + 1 >= SLOTS);
            u32 fAH = needAH ? flag_peek(aH + (t2 + 1 - SLOTS)) : 1u;
            if (t2 + 1 < T_) {
                // h1[t2+1]: system (cross-XCD, slack-hidden); h2[t2]: ring (live edge)
                stage_poll(smem, H1W_OFF, h1w + (size_t)(((t2+1) & 7)*2 + bhalf)*NWORD,
                           (u32)(t2 + 2), tid, soff);
                stage_poll_r(smem, H2W_OFF, rbuf + (size_t)(t2 & 7)*NWORD,
                             h2w + (size_t)((t2 & 7)*2 + bhalf)*NWORD,
                             (u32)(t2 + 1), tid, soff, coh, esc);
            }
            if (needAH && fAH < 1u) wait_ge(aH + (t2 + 1 - SLOTS), 1u);
            __syncthreads();
        }
    } else {
        // ================= head =================
        const int bhalf = role - 128;
        const int nt = w & 3, kh = w >> 2;
        half8 wr[8];
        #pragma unroll
        for (int k = 0; k < 8; ++k) {
            const int kt = kh*8 + k;
            wr[k] = *(const half8*)(Wop + ((size_t)(nt*16 + kt)*64 + lane)*8);
        }
        const float boutr = bout[nt*16 + col];
        u32* aH = arrH + bhalf*1024;
        const int lb0 = col, lb1 = 16 + col;

        stage_poll(smem, H1W_OFF, h2w + (size_t)(0*2 + bhalf)*NWORD, 1u, tid, soff);
        __syncthreads();
        if (tid == 0) flag_add(aH + 0);

        for (int t3 = 0; t3 < T_; ++t3) {
            floatx4 acc0 = {0.f,0.f,0.f,0.f}, acc1 = {0.f,0.f,0.f,0.f};
            #pragma unroll
            for (int k = 0; k < 8; ++k) {
                const int kc = (kh*8 + k)*4 + quad;
                half8 a0  = frag_pk(smem + H1W_OFF + WB(kc>>1, lb0, (kc&1)*3));
                half8 a1v = frag_pk(smem + H1W_OFF + WB(kc>>1, lb1, (kc&1)*3));
                acc0 = MFMA16(a0,  wr[k], acc0);
                acc1 = MFMA16(a1v, wr[k], acc1);
            }
            if (kh == 1) {
                #pragma unroll
                for (int r = 0; r < 4; ++r) {
                    RED[(nt*2+0)*256 + (quad*4 + r)*16 + col] = acc0[r];
                    RED[(nt*2+1)*256 + (quad*4 + r)*16 + col] = acc1[r];
                }
            }
            __syncthreads();
            if (kh == 0) {
                #pragma unroll
                for (int r = 0; r < 4; ++r) {
                    const float v0 = acc0[r] + RED[(nt*2+0)*256 + (quad*4 + r)*16 + col] + boutr;
                    const float v1 = acc1[r] + RED[(nt*2+1)*256 + (quad*4 + r)*16 + col] + boutr;
                    const int b0 = bhalf*32 +  0 + quad*4 + r;
                    const int b1 = bhalf*32 + 16 + quad*4 + r;
                    y[((size_t)b0*T_ + t3)*OUT_ + nt*16 + col] = v0;
                    y[((size_t)b1*T_ + t3)*OUT_ + nt*16 + col] = v1;
                }
            }
            __syncthreads();
            if (t3 + 1 < T_) {
                stage_poll(smem, H1W_OFF, h2w + (size_t)(((t3+1) & 7)*2 + bhalf)*NWORD,
                           (u32)(t3 + 2), tid, soff);
                __syncthreads();
                if (tid == 0) flag_add(aH + (t3 + 1));
            }
        }
    }
}

// ---------------- launch ----------------
extern "C" void kernel_launch(void* const* d_in, const int* in_sizes, int n_in,
                              void* d_out, int out_size, void* d_ws, size_t ws_size,
                              hipStream_t stream) {
    const float* x    = (const float*)d_in[0];
    const float* Wih1 = (const float*)d_in[1];
    const float* Whh1 = (const float*)d_in[2];
    const float* bih1 = (const float*)d_in[3];
    const float* bhh1 = (const float*)d_in[4];
    const float* Wih2 = (const float*)d_in[5];
    const float* Whh2 = (const float*)d_in[6];
    const float* bih2 = (const float*)d_in[7];
    const float* bhh2 = (const float*)d_in[8];
    const float* Wout = (const float*)d_in[9];
    const float* bout = (const float*)d_in[10];
    float* y = (float*)d_out;

    char* ws = (char*)d_ws;
    f16*   W1p   = (f16*)(ws + 0);           // 2,359,296 B
    f16*   W2p   = (f16*)(ws + 2359296);     // 4,194,304 B
    f16*   Wop   = (f16*)(ws + 6553600);     //    65,536 B
    float* bs1   = (float*)(ws + 6619136);   //     8,192 B
    float* bs2   = (float*)(ws + 6627328);   //     8,192 B
    u64*   h1w   = (u64*)(ws + 6635520);     //   786,432 B
    u64*   h2w   = (u64*)(ws + 7421952);     //   786,432 B
    u32*   arr2  = (u32*)(ws + 8208384);     //     8,192 B
    u32*   arrH  = (u32*)(ws + 8216576);     //     8,192 B
    u64*   hring = (u64*)(ws + 8224768);     // 1,572,864 B (4 rings x 8 slots)
    u32*   ctrl  = (u32*)(ws + 9797632);     //     1,168 B

    // zero tagged buffers (tag 0 = step -1 state), counters, rings, ctrl
    hipMemsetAsync(ws + 6635520, 0, 3163280, stream);

    pack_w1<<<4608, 256, 0, stream>>>(Wih1, Whh1, W1p);
    pack_w2<<<8192, 256, 0, stream>>>(Wih2, Whh2, W2p);
    pack_wo<<<128, 256, 0, stream>>>(Wout, Wop);
    bias_sum<<<8, 256, 0, stream>>>(bih1, bhh1, bih2, bhh2, bs1, bs2);

    lstm_persist<<<NWG, 512, 0, stream>>>(x, W1p, W2p, Wop, bs1, bs2, bout,
                                          h1w, h2w, hring, y, arr2, arrH, ctrl);
}

// Round 10
// 4198.111 us; speedup vs baseline: 1.6929x; 1.0416x over previous
//
#include <hip/hip_runtime.h>

#define B_    64
#define T_    1024
#define IN_   64
#define H_    512
#define OUT_  64
#define SLOTS 8
#define NWG   256
#define NROLE 130
#define NWORD 6144      // words per (bhalf, slot): 32 jt * 32 rows * 6 words
#define RSLOT (8*NWORD) // words per ring (8 slots)

typedef _Float16 f16;
typedef _Float16 half8 __attribute__((ext_vector_type(8)));
typedef float    floatx4 __attribute__((ext_vector_type(4)));
typedef unsigned int u32;
typedef unsigned short u16;
typedef unsigned long long u64;

#define MFMA16(a,b,c) __builtin_amdgcn_mfma_f32_16x16x32_f16((a),(b),(c),0,0,0)

// LDS layout (158720 B, 1 WG/CU)
#define XS_OFF   0        // 8KB: L1 x-stage (L2 reuses first 4B as esc flag)
#define HB_OFF   8192     // 1KB: pointwise h output (f16[512])
#define CC_OFF   9216     // 2KB: c-state
#define RED_OFF  11264    // 32KB: 4 kq-regions x 8KB partial-sum
#define H1W_OFF  44032    // 57344: packed h words (h1 for L1/L2; h2 for head)
#define H2W_OFF  101376   // 57344: packed h2 words (L2 pass B; L1 reuses first 4B as esc)

__device__ __forceinline__ float sigmoidf_(float x) {
    return 1.0f / (1.0f + __expf(-x));
}
__device__ __forceinline__ float tanhf_(float x) {
    float ax = fabsf(x);
    float e  = __expf(-2.0f * ax);
    float t  = (1.0f - e) / (1.0f + e);
    return x >= 0.0f ? t : -t;
}

// Flags: agent-scope RMW + agent-scope poll (proven R2/R5). Back-pressure edges only.
__device__ __forceinline__ u32 flag_peek(const u32* p) {
    return __hip_atomic_load(p, __ATOMIC_RELAXED, __HIP_MEMORY_SCOPE_AGENT);
}
__device__ __forceinline__ void wait_ge(u32* p, u32 v) {
    while (__hip_atomic_load(p, __ATOMIC_RELAXED, __HIP_MEMORY_SCOPE_AGENT) < v)
        __builtin_amdgcn_s_sleep(1);
}
__device__ __forceinline__ void flag_add(u32* p) {
    __hip_atomic_fetch_add(p, 1u, __ATOMIC_RELAXED, __HIP_MEMORY_SCOPE_AGENT);
}
// System-scope tagged-word ops (MALL coherence point) -- cross-XCD edges. Proven R9.
__device__ __forceinline__ void astore8w(u64* p, u64 v) {
    __hip_atomic_store(p, v, __ATOMIC_RELAXED, __HIP_MEMORY_SCOPE_SYSTEM);
}
__device__ __forceinline__ u64 aload8w(const u64* p) {
    return __hip_atomic_load(p, __ATOMIC_RELAXED, __HIP_MEMORY_SCOPE_SYSTEM);
}
// Agent-scope tagged-word ops -- intra-XCD ring edges (shared XCD L2 is the
// physical coherence point when all ring members sit on one XCD). Proven R14
// (FETCH_SIZE 866->215 MB).
__device__ __forceinline__ void astore8a(u64* p, u64 v) {
    __hip_atomic_store(p, v, __ATOMIC_RELAXED, __HIP_MEMORY_SCOPE_AGENT);
}
__device__ __forceinline__ u64 aload8a(const u64* p) {
    return __hip_atomic_load(p, __ATOMIC_RELAXED, __HIP_MEMORY_SCOPE_AGENT);
}

// Poll-stage ONE 49KB tagged buffer (6144 words) into LDS. 12-load rounds (R11
// lesson: never widen rounds).
__device__ __forceinline__ void stage_poll(char* smem, int ldsOff, const u64* g,
                                           u32 exp, int tid, const int* soff) {
    u32 pend = 0xFFFu;
    do {
        u64 vv[12];
        #pragma unroll
        for (int i = 0; i < 12; ++i)
            vv[i] = aload8w(g + i*512 + tid);
        #pragma unroll
        for (int i = 0; i < 12; ++i) {
            if ((pend & (1u << i)) && (u32)(vv[i] >> 48) == exp) {
                *(u64*)(smem + ldsOff + soff[i]) = vv[i];
                pend &= ~(1u << i);
            }
        }
        if (pend) __builtin_amdgcn_s_sleep(1);
    } while (pend);
}

// Ring poll: agent-scope loads from the ring copy (gr) when the ring is
// XCD-coherent; system loads from the always-published system copy (gs) when
// not, or after a sticky escape (safety: completes even if agent semantics
// differ from the hypothesis -- at R9 speed, never wrong, never hung).
__device__ __forceinline__ void stage_poll_r(char* smem, int ldsOff,
                                             const u64* gr, const u64* gs,
                                             u32 exp, int tid, const int* soff,
                                             int coh, int* esc) {
    u32 pend = 0xFFFu;
    int rounds = 0;
    bool useSys = (!coh) || (*esc != 0);
    do {
        u64 vv[12];
        if (!useSys) {
            #pragma unroll
            for (int i = 0; i < 12; ++i) vv[i] = aload8a(gr + i*512 + tid);
        } else {
            #pragma unroll
            for (int i = 0; i < 12; ++i) vv[i] = aload8w(gs + i*512 + tid);
        }
        #pragma unroll
        for (int i = 0; i < 12; ++i) {
            if ((pend & (1u << i)) && (u32)(vv[i] >> 48) == exp) {
                *(u64*)(smem + ldsOff + soff[i]) = vv[i];
                pend &= ~(1u << i);
            }
        }
        if (pend) {
            __builtin_amdgcn_s_sleep(1);
            if (!useSys && ++rounds >= 1024) { useSys = true; *esc = 1; }
        }
    } while (pend);
}

// Build a half8 fragment (8 consecutive k-values) from 3 packed LDS words.
__device__ __forceinline__ half8 frag_pk(const char* p) {
    const u64* q = (const u64*)p;
    u64 w0 = q[0], w1 = q[1], w2 = q[2];
    u32 b = (u32)(w0 >> 32), c = (u32)w1, d = (u32)(w1 >> 32);
    union { u32 u[4]; half8 h; } U;
    U.u[0] = (u32)w0;
    U.u[1] = (b & 0xffffu) | (c << 16);
    U.u[2] = (c >> 16) | (d << 16);
    U.u[3] = (u32)w2;
    return U.h;
}
// LDS byte offset of word (jt, row, wi): ((jt*32+row)*7 + wi)*8
#define WB(jt,row,wi) (((jt)*224 + (row)*7 + (wi)) * 8)

// ---------------- prep kernels (weights -> fp16 fragment-linear) ----------------
__global__ void pack_w1(const float* __restrict__ Wih, const float* __restrict__ Whh,
                        f16* __restrict__ Wp) {
    int idx = blockIdx.x * 256 + threadIdx.x;
    if (idx >= 4*32*18*512) return;
    int j    = idx & 7;
    int lane = (idx >> 3) & 63;
    int kt   = (idx >> 9) % 18;
    int r    = (idx >> 9) / 18;
    int jt   = r & 31;
    int g    = r >> 5;
    int n = g*512 + jt*16 + (lane & 15);
    int k = kt*32 + (lane >> 4)*8 + j;
    float v = (k < 64) ? Wih[n*64 + k] : Whh[n*512 + (k - 64)];
    Wp[idx] = (f16)v;
}

__global__ void pack_w2(const float* __restrict__ Wih, const float* __restrict__ Whh,
                        f16* __restrict__ Wp) {
    int idx = blockIdx.x * 256 + threadIdx.x;
    if (idx >= 4*32*32*512) return;
    int j    = idx & 7;
    int lane = (idx >> 3) & 63;
    int kt   = (idx >> 9) & 31;
    int r    = idx >> 14;
    int jt   = r & 31;
    int g    = r >> 5;
    int n = g*512 + jt*16 + (lane & 15);
    int k = kt*32 + (lane >> 4)*8 + j;
    float v = (k < 512) ? Wih[n*512 + k] : Whh[n*512 + (k - 512)];
    Wp[idx] = (f16)v;
}

__global__ void pack_wo(const float* __restrict__ Wout, f16* __restrict__ Wp) {
    int idx = blockIdx.x * 256 + threadIdx.x;
    if (idx >= 4*16*512) return;
    int j    = idx & 7;
    int lane = (idx >> 3) & 63;
    int kt   = (idx >> 9) & 15;
    int nt   = idx >> 13;
    int n = nt*16 + (lane & 15);
    int k = kt*32 + (lane >> 4)*8 + j;
    Wp[idx] = (f16)Wout[n*512 + k];
}

__global__ void bias_sum(const float* __restrict__ a1, const float* __restrict__ b1,
                         const float* __restrict__ a2, const float* __restrict__ b2,
                         float* __restrict__ s1, float* __restrict__ s2) {
    int i = blockIdx.x * 256 + threadIdx.x;
    if (i >= 2048) return;
    s1[i] = a1[i] + b1[i];
    s2[i] = a2[i] + b2[i];
}

// ---------------- persistent self-timed kernel ----------------
// R15 = R14 (rings, 4380 us) + ONE change in L2: prefetch-verify the h1 stage.
// h1[t2+1] is slack-hidden (L1 runs ring-fast, pinned 8 slots ahead), so its
// "poll" always succeeds round 1 -- i.e. it is a batch load + verify paying a
// serial ~1us MALL RT in the tail. R15 issues the 12 system loads right after
// pass A (H1W LDS is dead there); the MALL RT rides under pass B + pointwise +
// publish; the tail just tag-checks + commits (fallback re-poll covers warm-up).
// Slot-clobber safety: overwrite of slot (t2+1)&7 requires a2[t2+1], which
// cannot fire while we are still in t2.
__global__ __launch_bounds__(512, 1) void lstm_persist(
    const float* __restrict__ x,
    const f16*  __restrict__ W1p,
    const f16*  __restrict__ W2p,
    const f16*  __restrict__ Wop,
    const float* __restrict__ bs1,
    const float* __restrict__ bs2,
    const float* __restrict__ bout,
    u64*  __restrict__ h1w,     // [8][2][6144] tagged words (system copy)
    u64*  __restrict__ h2w,     // [8][2][6144] (system copy)
    u64*  __restrict__ hring,   // [4 rings][8][6144] ring-local copies
    float* __restrict__ y,
    u32*  __restrict__ arr2,    // [2][1024]
    u32*  __restrict__ arrH,    // [2][1024]
    u32*  __restrict__ ctrl)    // claim/ring-init control block
{
    __shared__ __align__(16) char smem[158720];
    __shared__ int s_role, s_coh;
    float* RED = (float*)(smem + RED_OFF);
    float* CC  = (float*)(smem + CC_OFF);

    const int tid  = threadIdx.x;
    const int lane = tid & 63;
    const int w    = tid >> 6;
    const int col  = lane & 15;
    const int quad = lane >> 4;

    // ---- role claim (tid 0) ----
    u32 xcd;
    asm volatile("s_getreg_b32 %0, hwreg(HW_REG_XCC_ID)" : "=s"(xcd));
    xcd &= 7u;
    if (tid == 0) {
        u32* cnt     = ctrl;          // [8]
        u32* claimed = ctrl + 8;      // [1]
        u32* taken   = ctrl + 16;     // [130]
        u32* mx      = ctrl + 160;    // [128] member xcd+1
        u32* rcnt    = ctrl + 288;    // [4]
        int role = -1;
        u32 rank = __hip_atomic_fetch_add(&cnt[xcd], 1u, __ATOMIC_RELAXED, __HIP_MEMORY_SCOPE_AGENT);
        int pref = -1;
        if (xcd < 4u)       { if (rank < 32u) pref = (int)(xcd*32u + rank); }
        else if (xcd == 4u) { if (rank < 2u)  pref = 128 + (int)rank; }
        if (pref >= 0) {
            u32 e0 = 0;
            if (__hip_atomic_compare_exchange_strong(&taken[pref], &e0, 1u,
                    __ATOMIC_RELAXED, __ATOMIC_RELAXED, __HIP_MEMORY_SCOPE_AGENT))
                role = pref;
        }
        if (role < 0) {
            if (pref < 0)   // courtesy delay so preferred owners claim first
                for (int s = 0; s < 100; ++s) __builtin_amdgcn_s_sleep(64);
            while (role < 0) {
                if (__hip_atomic_load(claimed, __ATOMIC_RELAXED, __HIP_MEMORY_SCOPE_AGENT) >= (u32)NROLE)
                    break;
                for (int r = 0; r < NROLE; ++r) {
                    u32 e0 = 0;
                    if (__hip_atomic_load(&taken[r], __ATOMIC_RELAXED, __HIP_MEMORY_SCOPE_AGENT) == 0u &&
                        __hip_atomic_compare_exchange_strong(&taken[r], &e0, 1u,
                            __ATOMIC_RELAXED, __ATOMIC_RELAXED, __HIP_MEMORY_SCOPE_AGENT)) {
                        role = r; break;
                    }
                }
            }
        }
        int coh = 0;
        if (role >= 0) {
            __hip_atomic_fetch_add(claimed, 1u, __ATOMIC_RELAXED, __HIP_MEMORY_SCOPE_AGENT);
            if (role < 128) {   // ring member: exchange XCDs, check coherence
                const int ring = role >> 5;
                __hip_atomic_store(&mx[role], xcd + 1u, __ATOMIC_RELAXED, __HIP_MEMORY_SCOPE_AGENT);
                __hip_atomic_fetch_add(&rcnt[ring], 1u, __ATOMIC_RELEASE, __HIP_MEMORY_SCOPE_AGENT);
                while (__hip_atomic_load(&rcnt[ring], __ATOMIC_ACQUIRE, __HIP_MEMORY_SCOPE_AGENT) < 32u)
                    __builtin_amdgcn_s_sleep(1);
                coh = 1;
                u32 x0 = __hip_atomic_load(&mx[ring*32], __ATOMIC_RELAXED, __HIP_MEMORY_SCOPE_AGENT);
                for (int i = 1; i < 32; ++i)
                    if (__hip_atomic_load(&mx[ring*32 + i], __ATOMIC_RELAXED, __HIP_MEMORY_SCOPE_AGENT) != x0)
                        coh = 0;
            }
        }
        s_role = role;
        s_coh  = coh;
    }
    __syncthreads();
    const int role = s_role;
    const int coh  = s_coh;
    if (role < 0) return;

    // staging LDS offsets for this thread's 12 words
    int soff[12];
    #pragma unroll
    for (int i = 0; i < 12; ++i) {
        const int ww = i*512 + tid;
        const int jt_ = ww / 192, rr = ww - jt_*192;
        soff[i] = WB(jt_, rr/6, rr%6);
    }
    // publisher params (valid for tid<192): word tid = r*6 + i of own slice
    const int pr  = tid / 6, pi = tid - pr*6;
    const int pj  = pi % 3;
    const int pc0 = pr*16 + (pi/3)*8 + pj*3;
    const u16* hb = (const u16*)(smem + HB_OFF);

    if (role < 64) {
        // ================= layer 1 =================
        const int bhalf = role >> 5, jt = role & 31;
        u64* rbuf = hring + (size_t)bhalf * RSLOT;      // ring 0/1
        int* esc  = (int*)(smem + H2W_OFF);             // L1 never uses H2W
        if (tid == 0) *esc = 0;
        const int gp = w & 1, kq = w >> 1;
        half8 wrx[2];
        half8 wrh[2][4];
        if (kq < 2) {
            #pragma unroll
            for (int gi = 0; gi < 2; ++gi)
                wrx[gi] = *(const half8*)(W1p + ((size_t)(((gp*2+gi)*32 + jt)*18 + kq)*64 + lane)*8);
        }
        #pragma unroll
        for (int gi = 0; gi < 2; ++gi)
            #pragma unroll
            for (int k = 0; k < 4; ++k) {
                const int kt = 2 + kq*4 + k;
                wrh[gi][k] = *(const half8*)(W1p + ((size_t)(((gp*2+gi)*32 + jt)*18 + kt)*64 + lane)*8);
            }
        float bsr[4];
        #pragma unroll
        for (int g = 0; g < 4; ++g) bsr[g] = bs1[g*512 + jt*16 + (tid & 15)];
        CC[tid] = 0.f;

        u32* a2 = arr2 + bhalf*1024;
        const int lbx = tid >> 4, kcx = tid & 15;
        const float* xbase = x + (size_t)(bhalf*32 + lbx)*T_*(size_t)IN_ + ((kcx ^ (lbx & 7)) * 4);

        // prologue: x_0 + h1[-1] (slot 7, tag 0 = zeroed buffers)
        *(float4*)(smem + XS_OFF + tid*16) = *(const float4*)xbase;
        __syncthreads();   // esc visible
        stage_poll_r(smem, H1W_OFF, rbuf + (size_t)7*NWORD,
                     h1w + (size_t)(7*2 + bhalf)*NWORD, 0u, tid, soff, coh, esc);
        __syncthreads();

        for (int t = 0; t < T_; ++t) {
            float4 xreg;
            if (t + 1 < T_) xreg = *(const float4*)(xbase + (size_t)(t+1)*IN_);

            floatx4 acc[2][2] = {{{0.f,0.f,0.f,0.f},{0.f,0.f,0.f,0.f}},
                                 {{0.f,0.f,0.f,0.f},{0.f,0.f,0.f,0.f}}};
            #pragma unroll
            for (int m = 0; m < 2; ++m) {
                const int lb_a = m*16 + col, sw = lb_a & 7;
                if (kq < 2) {
                    const int fg = kq*8 + quad*2;
                    float4 u = *(const float4*)(smem + XS_OFF + ((size_t)lb_a*16 + (fg ^ sw))*16);
                    float4 v = *(const float4*)(smem + XS_OFF + ((size_t)lb_a*16 + ((fg+1) ^ sw))*16);
                    half8 a = (half8){(f16)u.x,(f16)u.y,(f16)u.z,(f16)u.w,
                                      (f16)v.x,(f16)v.y,(f16)v.z,(f16)v.w};
                    acc[0][m] = MFMA16(a, wrx[0], acc[0][m]);
                    acc[1][m] = MFMA16(a, wrx[1], acc[1][m]);
                }
                #pragma unroll
                for (int k = 0; k < 4; ++k) {
                    const int kc = kq*16 + k*4 + quad;
                    half8 a = frag_pk(smem + H1W_OFF + WB(kc>>1, lb_a, (kc&1)*3));
                    acc[0][m] = MFMA16(a, wrh[0][k], acc[0][m]);
                    acc[1][m] = MFMA16(a, wrh[1][k], acc[1][m]);
                }
            }
            #pragma unroll
            for (int gi = 0; gi < 2; ++gi) {
                const int g = gp*2 + gi;
                #pragma unroll
                for (int m = 0; m < 2; ++m)
                    #pragma unroll
                    for (int r = 0; r < 4; ++r)
                        RED[kq*2048 + g*512 + (m*16 + quad*4 + r)*16 + col] = acc[gi][m][r];
            }
            __syncthreads();
            {   // 4-way kq sum + pointwise -> HB
                float gt[4];
                #pragma unroll
                for (int g = 0; g < 4; ++g)
                    gt[g] = RED[       g*512 + tid] + RED[2048 + g*512 + tid]
                          + RED[4096 + g*512 + tid] + RED[6144 + g*512 + tid] + bsr[g];
                const float i_ = sigmoidf_(gt[0]);
                const float f_ = sigmoidf_(gt[1]);
                const float g_ = tanhf_(gt[2]);
                const float o_ = sigmoidf_(gt[3]);
                const float cn = f_ * CC[tid] + i_ * g_;
                CC[tid] = cn;
                ((f16*)(smem + HB_OFF))[tid] = (f16)(o_ * tanhf_(cn));
            }
            __syncthreads();
            // publish h1[t]: system copy always (L2 consumes); ring copy if coherent
            if (tid < 192) {
                u64 wv = (u64)hb[pc0] | ((u64)hb[pc0+1] << 16)
                       | ((pj < 2) ? ((u64)hb[pc0+2] << 32) : 0)
                       | ((u64)(u32)(t + 1) << 48);
                astore8w(h1w + (size_t)((t & 7)*2 + bhalf)*NWORD + jt*192 + tid, wv);
                if (coh) astore8a(rbuf + (size_t)(t & 7)*NWORD + jt*192 + tid, wv);
            }
            const bool needA2 = (tid == 0) && (t + 1 < T_) && (t + 1 >= SLOTS);
            u32 fA2 = needA2 ? flag_peek(a2 + (t + 1 - SLOTS)) : 32u;
            if (t + 1 < T_) {
                *(float4*)(smem + XS_OFF + tid*16) = xreg;
                stage_poll_r(smem, H1W_OFF, rbuf + (size_t)(t & 7)*NWORD,
                             h1w + (size_t)((t & 7)*2 + bhalf)*NWORD,
                             (u32)(t + 1), tid, soff, coh, esc);
            }
            if (needA2 && fA2 < 32u) wait_ge(a2 + (t + 1 - SLOTS), 32u);
            __syncthreads();
        }
    } else if (role < 128) {
        // ================= layer 2 =================
        const int v = role - 64;
        const int bhalf = v >> 5, jt = v & 31;
        u64* rbuf = hring + (size_t)(2 + bhalf) * RSLOT;   // ring 2/3
        int* esc  = (int*)(smem + XS_OFF);                 // L2 never uses XS
        if (tid == 0) *esc = 0;
        const int gp = w & 1, kq = w >> 1;
        half8 wrA[2][4], wrB[2][4];
        #pragma unroll
        for (int gi = 0; gi < 2; ++gi)
            #pragma unroll
            for (int k = 0; k < 4; ++k) {
                const int ktA = kq*4 + k;
                const int ktB = 16 + kq*4 + k;
                wrA[gi][k] = *(const half8*)(W2p + ((size_t)(((gp*2+gi)*32 + jt)*32 + ktA)*64 + lane)*8);
                wrB[gi][k] = *(const half8*)(W2p + ((size_t)(((gp*2+gi)*32 + jt)*32 + ktB)*64 + lane)*8);
            }
        float bsr[4];
        #pragma unroll
        for (int g = 0; g < 4; ++g) bsr[g] = bs2[g*512 + jt*16 + (tid & 15)];
        CC[tid] = 0.f;

        u32* a2 = arr2 + bhalf*1024;
        u32* aH = arrH + bhalf*1024;

        // prologue: h1[0] (system, tag 1) then h2[-1] (ring/system, slot 7 tag 0)
        __syncthreads();   // esc visible
        stage_poll(smem, H1W_OFF, h1w + (size_t)(0*2 + bhalf)*NWORD, 1u, tid, soff);
        stage_poll_r(smem, H2W_OFF, rbuf + (size_t)7*NWORD,
                     h2w + (size_t)(7*2 + bhalf)*NWORD, 0u, tid, soff, coh, esc);
        __syncthreads();

        for (int t2 = 0; t2 < T_; ++t2) {
            floatx4 acc[2][2] = {{{0.f,0.f,0.f,0.f},{0.f,0.f,0.f,0.f}},
                                 {{0.f,0.f,0.f,0.f},{0.f,0.f,0.f,0.f}}};
            #pragma unroll
            for (int m = 0; m < 2; ++m) {   // pass A (h1[t2])
                const int lb_a = m*16 + col;
                #pragma unroll
                for (int k = 0; k < 4; ++k) {
                    const int kc = kq*16 + k*4 + quad;
                    half8 a = frag_pk(smem + H1W_OFF + WB(kc>>1, lb_a, (kc&1)*3));
                    acc[0][m] = MFMA16(a, wrA[0][k], acc[0][m]);
                    acc[1][m] = MFMA16(a, wrA[1][k], acc[1][m]);
                }
            }
            // EARLY ISSUE (R15): h1[t2+1] system loads -> registers. H1W LDS is
            // dead after pass A; the ~1us MALL RT hides under pass B + pointwise
            // + publish. Tag-checked + committed in the tail.
            u64 h1r[12];
            const u64* g1n = h1w + (size_t)(((t2+1) & 7)*2 + bhalf)*NWORD;
            if (t2 + 1 < T_) {
                #pragma unroll
                for (int i = 0; i < 12; ++i) h1r[i] = aload8w(g1n + i*512 + tid);
            }
            #pragma unroll
            for (int m = 0; m < 2; ++m) {   // pass B (h2[t2-1])
                const int lb_a = m*16 + col;
                #pragma unroll
                for (int k = 0; k < 4; ++k) {
                    const int kc = kq*16 + k*4 + quad;
                    half8 a = frag_pk(smem + H2W_OFF + WB(kc>>1, lb_a, (kc&1)*3));
                    acc[0][m] = MFMA16(a, wrB[0][k], acc[0][m]);
                    acc[1][m] = MFMA16(a, wrB[1][k], acc[1][m]);
                }
            }
            #pragma unroll
            for (int gi = 0; gi < 2; ++gi) {
                const int g = gp*2 + gi;
                #pragma unroll
                for (int m = 0; m < 2; ++m)
                    #pragma unroll
                    for (int r = 0; r < 4; ++r)
                        RED[kq*2048 + g*512 + (m*16 + quad*4 + r)*16 + col] = acc[gi][m][r];
            }
            __syncthreads();
            {   // 4-way kq sum + pointwise -> HB
                float gt[4];
                #pragma unroll
                for (int g = 0; g < 4; ++g)
                    gt[g] = RED[       g*512 + tid] + RED[2048 + g*512 + tid]
                          + RED[4096 + g*512 + tid] + RED[6144 + g*512 + tid] + bsr[g];
                const float i_ = sigmoidf_(gt[0]);
                const float f_ = sigmoidf_(gt[1]);
                const float g_ = tanhf_(gt[2]);
                const float o_ = sigmoidf_(gt[3]);
                const float cn = f_ * CC[tid] + i_ * g_;
                CC[tid] = cn;
                ((f16*)(smem + HB_OFF))[tid] = (f16)(o_ * tanhf_(cn));
            }
            __syncthreads();
            // publish h2[t2]: system copy always (head consumes); ring copy if coherent
            if (tid < 192) {
                u64 wv = (u64)hb[pc0] | ((u64)hb[pc0+1] << 16)
                       | ((pj < 2) ? ((u64)hb[pc0+2] << 32) : 0)
                       | ((u64)(u32)(t2 + 1) << 48);
                astore8w(h2w + (size_t)((t2 & 7)*2 + bhalf)*NWORD + jt*192 + tid, wv);
                if (coh) astore8a(rbuf + (size_t)(t2 & 7)*NWORD + jt*192 + tid, wv);
            }
            if (tid == 0) flag_add(a2 + t2);
            const bool needAH = (tid == 0) && (t2 + 1 < T_) && (t2 + 1 >= SLOTS);
            u32 fAH = needAH ? flag_peek(aH + (t2 + 1 - SLOTS)) : 1u;
            if (t2 + 1 < T_) {
                // commit h1[t2+1] (loads issued after pass A; data returned long ago)
                u32 pend = 0xFFFu;
                #pragma unroll
                for (int i = 0; i < 12; ++i) {
                    if ((u32)(h1r[i] >> 48) == (u32)(t2 + 2)) {
                        *(u64*)(smem + H1W_OFF + soff[i]) = h1r[i];
                        pend &= ~(1u << i);
                    }
                }
                while (pend) {   // rare (warm-up): straggler re-poll
                    u64 vv[12];
                    #pragma unroll
                    for (int i = 0; i < 12; ++i) vv[i] = aload8w(g1n + i*512 + tid);
                    #pragma unroll
                    for (int i = 0; i < 12; ++i) {
                        if ((pend & (1u << i)) && (u32)(vv[i] >> 48) == (u32)(t2 + 2)) {
                            *(u64*)(smem + H1W_OFF + soff[i]) = vv[i];
                            pend &= ~(1u << i);
                        }
                    }
                    if (pend) __builtin_amdgcn_s_sleep(1);
                }
                // live edge: h2[t2] ring poll
                stage_poll_r(smem, H2W_OFF, rbuf + (size_t)(t2 & 7)*NWORD,
                             h2w + (size_t)((t2 & 7)*2 + bhalf)*NWORD,
                             (u32)(t2 + 1), tid, soff, coh, esc);
            }
            if (needAH && fAH < 1u) wait_ge(aH + (t2 + 1 - SLOTS), 1u);
            __syncthreads();
        }
    } else {
        // ================= head =================
        const int bhalf = role - 128;
        const int nt = w & 3, kh = w >> 2;
        half8 wr[8];
        #pragma unroll
        for (int k = 0; k < 8; ++k) {
            const int kt = kh*8 + k;
            wr[k] = *(const half8*)(Wop + ((size_t)(nt*16 + kt)*64 + lane)*8);
        }
        const float boutr = bout[nt*16 + col];
        u32* aH = arrH + bhalf*1024;
        const int lb0 = col, lb1 = 16 + col;

        stage_poll(smem, H1W_OFF, h2w + (size_t)(0*2 + bhalf)*NWORD, 1u, tid, soff);
        __syncthreads();
        if (tid == 0) flag_add(aH + 0);

        for (int t3 = 0; t3 < T_; ++t3) {
            floatx4 acc0 = {0.f,0.f,0.f,0.f}, acc1 = {0.f,0.f,0.f,0.f};
            #pragma unroll
            for (int k = 0; k < 8; ++k) {
                const int kc = (kh*8 + k)*4 + quad;
                half8 a0  = frag_pk(smem + H1W_OFF + WB(kc>>1, lb0, (kc&1)*3));
                half8 a1v = frag_pk(smem + H1W_OFF + WB(kc>>1, lb1, (kc&1)*3));
                acc0 = MFMA16(a0,  wr[k], acc0);
                acc1 = MFMA16(a1v, wr[k], acc1);
            }
            if (kh == 1) {
                #pragma unroll
                for (int r = 0; r < 4; ++r) {
                    RED[(nt*2+0)*256 + (quad*4 + r)*16 + col] = acc0[r];
                    RED[(nt*2+1)*256 + (quad*4 + r)*16 + col] = acc1[r];
                }
            }
            __syncthreads();
            if (kh == 0) {
                #pragma unroll
                for (int r = 0; r < 4; ++r) {
                    const float v0 = acc0[r] + RED[(nt*2+0)*256 + (quad*4 + r)*16 + col] + boutr;
                    const float v1 = acc1[r] + RED[(nt*2+1)*256 + (quad*4 + r)*16 + col] + boutr;
                    const int b0 = bhalf*32 +  0 + quad*4 + r;
                    const int b1 = bhalf*32 + 16 + quad*4 + r;
                    y[((size_t)b0*T_ + t3)*OUT_ + nt*16 + col] = v0;
                    y[((size_t)b1*T_ + t3)*OUT_ + nt*16 + col] = v1;
                }
            }
            __syncthreads();
            if (t3 + 1 < T_) {
                stage_poll(smem, H1W_OFF, h2w + (size_t)(((t3+1) & 7)*2 + bhalf)*NWORD,
                           (u32)(t3 + 2), tid, soff);
                __syncthreads();
                if (tid == 0) flag_add(aH + (t3 + 1));
            }
        }
    }
}

// ---------------- launch ----------------
extern "C" void kernel_launch(void* const* d_in, const int* in_sizes, int n_in,
                              void* d_out, int out_size, void* d_ws, size_t ws_size,
                              hipStream_t stream) {
    const float* x    = (const float*)d_in[0];
    const float* Wih1 = (const float*)d_in[1];
    const float* Whh1 = (const float*)d_in[2];
    const float* bih1 = (const float*)d_in[3];
    const float* bhh1 = (const float*)d_in[4];
    const float* Wih2 = (const float*)d_in[5];
    const float* Whh2 = (const float*)d_in[6];
    const float* bih2 = (const float*)d_in[7];
    const float* bhh2 = (const float*)d_in[8];
    const float* Wout = (const float*)d_in[9];
    const float* bout = (const float*)d_in[10];
    float* y = (float*)d_out;

    char* ws = (char*)d_ws;
    f16*   W1p   = (f16*)(ws + 0);           // 2,359,296 B
    f16*   W2p   = (f16*)(ws + 2359296);     // 4,194,304 B
    f16*   Wop   = (f16*)(ws + 6553600);     //    65,536 B
    float* bs1   = (float*)(ws + 6619136);   //     8,192 B
    float* bs2   = (float*)(ws + 6627328);   //     8,192 B
    u64*   h1w   = (u64*)(ws + 6635520);     //   786,432 B
    u64*   h2w   = (u64*)(ws + 7421952);     //   786,432 B
    u32*   arr2  = (u32*)(ws + 8208384);     //     8,192 B
    u32*   arrH  = (u32*)(ws + 8216576);     //     8,192 B
    u64*   hring = (u64*)(ws + 8224768);     // 1,572,864 B (4 rings x 8 slots)
    u32*   ctrl  = (u32*)(ws + 9797632);     //     1,168 B

    // zero tagged buffers (tag 0 = step -1 state), counters, rings, ctrl
    hipMemsetAsync(ws + 6635520, 0, 3163280, stream);

    pack_w1<<<4608, 256, 0, stream>>>(Wih1, Whh1, W1p);
    pack_w2<<<8192, 256, 0, stream>>>(Wih2, Whh2, W2p);
    pack_wo<<<128, 256, 0, stream>>>(Wout, Wop);
    bias_sum<<<8, 256, 0, stream>>>(bih1, bhh1, bih2, bhh2, bs1, bs2);

    lstm_persist<<<NWG, 512, 0, stream>>>(x, W1p, W2p, Wop, bs1, bs2, bout,
                                          h1w, h2w, hring, y, arr2, arrH, ctrl);
}